// Round 2
// baseline (18948.636 us; speedup 1.0000x reference)
//
#include <hip/hip_runtime.h>
#include <hip/hip_bf16.h>
#include <math.h>

// ---- problem constants ----
#define BATCH  2
#define S_TOK  2046
#define NCOND  2
#define SEQ    2048
#define DMODEL 512
#define DINNER 2048
#define NHEAD  8
#define DHEAD  64
#define NLAYER 6
#define VOCAB  512
#define MROWS  (BATCH*SEQ)   // 4096 rows

// ---------------------------------------------------------------------------
// Generic tiled GEMM: C[M,N] = A[M,K] @ W[K,N] + bias (all fp32), fused
// epilogues. mode 0: +bias ; 1: +bias+R ; 2: relu(+bias)+chord
// 64x64 tile, BK=16, 256 threads, 4x4 per thread.
// ---------------------------------------------------------------------------
__global__ __launch_bounds__(256) void gemm_kernel(
    const float* __restrict__ A, const float* __restrict__ W,
    const float* __restrict__ bias, const float* __restrict__ R,
    float* __restrict__ C,
    int M, int N, int K, int mode,
    const float* __restrict__ ttc, const float* __restrict__ ttcW,
    const float* __restrict__ ttcb)
{
  __shared__ float As[16][65];   // [k][m], +1 pad kills store conflicts
  __shared__ float Ws[16][64];   // [k][n]
  const int tid = threadIdx.x;
  const int tn = tid & 15, tm = tid >> 4;
  const int row0 = blockIdx.x * 64, col0 = blockIdx.y * 64;
  float acc[4][4] = {};

  for (int k0 = 0; k0 < K; k0 += 16) {
#pragma unroll
    for (int i = 0; i < 4; i++) {
      int li = tid + i * 256;
      int r = li >> 4, c = li & 15;
      As[c][r] = A[(size_t)(row0 + r) * K + (k0 + c)];
    }
#pragma unroll
    for (int i = 0; i < 4; i++) {
      int li = tid + i * 256;
      int r = li >> 6, c = li & 63;
      Ws[r][c] = W[(size_t)(k0 + r) * N + (col0 + c)];
    }
    __syncthreads();
#pragma unroll
    for (int k = 0; k < 16; k++) {
      float a[4], w[4];
#pragma unroll
      for (int i = 0; i < 4; i++) a[i] = As[k][tm * 4 + i];
#pragma unroll
      for (int i = 0; i < 4; i++) w[i] = Ws[k][tn * 4 + i];
#pragma unroll
      for (int ii = 0; ii < 4; ii++)
#pragma unroll
        for (int jj = 0; jj < 4; jj++)
          acc[ii][jj] = fmaf(a[ii], w[jj], acc[ii][jj]);
    }
    __syncthreads();
  }

#pragma unroll
  for (int ii = 0; ii < 4; ii++) {
    int m = row0 + tm * 4 + ii;
    float tval = 0.f;
    if (mode == 2) {           // chord scalar for this row
      int b = m >> 11, s = m & (SEQ - 1);
      int sp = (s < NCOND) ? 0 : (s - NCOND);
      tval = 8.0f - ttc[b * S_TOK + sp];
    }
#pragma unroll
    for (int jj = 0; jj < 4; jj++) {
      int n = col0 + tn * 4 + jj;
      float v = acc[ii][jj] + bias[n];
      if (mode == 1)      v += R[(size_t)m * N + n];
      else if (mode == 2) v = fmaxf(v, 0.f) + tval * ttcW[n] + ttcb[n];
      C[(size_t)m * N + n] = v;
    }
  }
}

// ---------------------------------------------------------------------------
// LayerNorm over D=512, one row per block (256 threads, 2 elems/thread).
// ---------------------------------------------------------------------------
__global__ __launch_bounds__(256) void ln_kernel(
    const float* __restrict__ X, const float* __restrict__ g,
    const float* __restrict__ bta, float* __restrict__ Y)
{
  int row = blockIdx.x, tid = threadIdx.x;
  const float* xr = X + (size_t)row * DMODEL;
  float x0 = xr[tid], x1 = xr[tid + 256];
  __shared__ float red[8];
  int wv = tid >> 6, ln = tid & 63;
  float s = x0 + x1;
  for (int off = 32; off; off >>= 1) s += __shfl_xor(s, off);
  if (ln == 0) red[wv] = s;
  __syncthreads();
  float mu = (red[0] + red[1] + red[2] + red[3]) * (1.0f / DMODEL);
  float d0 = x0 - mu, d1 = x1 - mu;
  float vs = d0 * d0 + d1 * d1;
  for (int off = 32; off; off >>= 1) vs += __shfl_xor(vs, off);
  if (ln == 0) red[4 + wv] = vs;
  __syncthreads();
  float var = (red[4] + red[5] + red[6] + red[7]) * (1.0f / DMODEL);
  float rstd = rsqrtf(var + 1e-6f);
  Y[(size_t)row * DMODEL + tid]       = d0 * rstd * g[tid]       + bta[tid];
  Y[(size_t)row * DMODEL + tid + 256] = d1 * rstd * g[tid + 256] + bta[tid + 256];
}

// ---------------------------------------------------------------------------
// Token embedding + positional add for rows s in [NCOND, SEQ).
// ---------------------------------------------------------------------------
__global__ __launch_bounds__(256) void tok_embed_kernel(
    const int* __restrict__ toks, const float* __restrict__ emb,
    const float* __restrict__ pos, float* __restrict__ x)
{
  int sp = blockIdx.x;          // 0..S_TOK-1
  int b  = blockIdx.y;
  int s  = sp + NCOND;
  int tok = toks[b * S_TOK + sp];
  const float* er = emb + (size_t)tok * DMODEL;
  const float* pr = pos + (size_t)s * DMODEL;
  float* xr = x + ((size_t)b * SEQ + s) * DMODEL;
  for (int d = threadIdx.x; d < DMODEL; d += 256)
    xr[d] = er[d] * 22.62741699796952f + pr[d];   // sqrt(512)
}

// ---------------------------------------------------------------------------
// Condition MLP rows (s < NCOND): ce = relu(c*W1+b1)@W2+b2 (nan -> null_cond),
// then + pos. One block per (ci, b).
// ---------------------------------------------------------------------------
__global__ __launch_bounds__(256) void cond_embed_kernel(
    const float* __restrict__ conds, const float* __restrict__ W1,
    const float* __restrict__ b1, const float* __restrict__ b2w,
    const float* __restrict__ b2, const float* __restrict__ nullc,
    const float* __restrict__ pos, float* __restrict__ x)
{
  int ci = blockIdx.x, b = blockIdx.y, tid = threadIdx.x;
  float c = conds[b * NCOND + ci];
  bool cn = isnan(c);
  float cm = cn ? 0.f : c;
  __shared__ float h1[DMODEL / 2];
  h1[tid] = fmaxf(cm * W1[ci * (DMODEL/2) + tid] + b1[ci * (DMODEL/2) + tid], 0.f);
  __syncthreads();
  for (int d = tid; d < DMODEL; d += 256) {
    float acc = b2[ci * DMODEL + d];
    for (int i = 0; i < DMODEL / 2; i++)
      acc = fmaf(h1[i], b2w[((size_t)ci * (DMODEL/2) + i) * DMODEL + d], acc);
    float ce = cn ? nullc[ci * DMODEL + d] : acc;
    x[((size_t)b * SEQ + ci) * DMODEL + d] = ce + pos[(size_t)ci * DMODEL + d];
  }
}

// ---------------------------------------------------------------------------
// Relative attention, flash-style, one wave per (b,h,query-row i).
// score(i,j) = q_i . (k_j + E[SEQ-1-i+j]) / 8 for j<=i and key j not PAD.
// O aliases Q: each wave's write set == its own private read slice.
// ---------------------------------------------------------------------------
__global__ __launch_bounds__(256) void attn_kernel(
    const float* Q, const float* __restrict__ K, const float* __restrict__ V,
    const float* __restrict__ E_l, const int* __restrict__ toks, float* O)
{
  int wid  = blockIdx.x * 4 + (threadIdx.x >> 6);
  int lane = threadIdx.x & 63;
  int i = wid & (SEQ - 1);
  int h = (wid >> 11) & (NHEAD - 1);
  int b = wid >> 14;

  float qv = Q[((size_t)(b * SEQ + i)) * DMODEL + h * DHEAD + lane];
  float m_run = -1e30f, l_run = 0.f, acc = 0.f;

  for (int j0 = 0; j0 <= i; j0 += 64) {
    int jj = j0 + lane;
    bool valid = (jj <= i);
    if (valid && jj >= NCOND) {
      if (toks[b * S_TOK + jj - NCOND] == 0) valid = false;   // key padding
    }
    int jr = (jj <= i) ? jj : i;            // clamp for safe addresses
    int me = (SEQ - 1) - i + jr;            // relative-E row
    const float* krow = K + ((size_t)(b * SEQ + jr)) * DMODEL + h * DHEAD;
    const float* erow = E_l + (size_t)me * DHEAD;
    float s = 0.f;
#pragma unroll 8
    for (int d = 0; d < DHEAD; d++) {
      float qd = __shfl(qv, d);
      s = fmaf(qd, krow[d] + erow[d], s);
    }
    s *= 0.125f;                            // 1/sqrt(64)
    if (!valid) s = -1e30f;

    float mx = s;
    for (int off = 32; off; off >>= 1) mx = fmaxf(mx, __shfl_xor(mx, off));
    float m_new = fmaxf(m_run, mx);
    float p = valid ? __expf(s - m_new) : 0.f;
    float ps = p;
    for (int off = 32; off; off >>= 1) ps += __shfl_xor(ps, off);
    float alpha = __expf(m_run - m_new);
    l_run = l_run * alpha + ps;
    acc *= alpha;

    int jmax = min(64, i - j0 + 1);
    const float* vbase = V + ((size_t)(b * SEQ + j0)) * DMODEL + h * DHEAD;
    for (int j = 0; j < jmax; j++) {
      float pj = __shfl(p, j);
      acc = fmaf(pj, vbase[(size_t)j * DMODEL + lane], acc);
    }
    m_run = m_new;
  }
  O[((size_t)(b * SEQ + i)) * DMODEL + h * DHEAD + lane] = acc / l_run;
}

// ---------------------------------------------------------------------------
extern "C" void kernel_launch(void* const* d_in, const int* in_sizes, int n_in,
                              void* d_out, int out_size, void* d_ws, size_t ws_size,
                              hipStream_t stream) {
  const int*   toks  = (const int*)  d_in[0];
  const float* conds = (const float*)d_in[1];
  const float* ttc   = (const float*)d_in[2];
  const float* emb   = (const float*)d_in[3];
  const float* pos   = (const float*)d_in[4];
  const float* cW1   = (const float*)d_in[5];
  const float* cb1   = (const float*)d_in[6];
  const float* cW2   = (const float*)d_in[7];
  const float* cb2   = (const float*)d_in[8];
  const float* nullc = (const float*)d_in[9];
  const float* ttcW  = (const float*)d_in[10];
  const float* ttcb  = (const float*)d_in[11];
  const float* Wq    = (const float*)d_in[12];
  const float* Wk    = (const float*)d_in[13];
  const float* Wv    = (const float*)d_in[14];
  const float* Wo    = (const float*)d_in[15];
  const float* bq    = (const float*)d_in[16];
  const float* bk    = (const float*)d_in[17];
  const float* bv    = (const float*)d_in[18];
  const float* bo    = (const float*)d_in[19];
  const float* E     = (const float*)d_in[20];
  const float* fW1   = (const float*)d_in[21];
  const float* fb1   = (const float*)d_in[22];
  const float* fW2   = (const float*)d_in[23];
  const float* fb2   = (const float*)d_in[24];
  const float* ln1g  = (const float*)d_in[25];
  const float* ln1b  = (const float*)d_in[26];
  const float* ln2g  = (const float*)d_in[27];
  const float* ln2b  = (const float*)d_in[28];
  const float* fcW   = (const float*)d_in[29];
  const float* fcb   = (const float*)d_in[30];

  float* ws = (float*)d_ws;
  const size_t MD = (size_t)MROWS * DMODEL;   // 2,097,152 floats = 8 MB
  float* x    = ws;            // current hidden state
  float* q    = ws + 1 * MD;   // q, then attention output
  float* k    = ws + 2 * MD;
  float* v    = ws + 3 * MD;
  float* t1   = ws + 4 * MD;   // pre-LN sums
  float* out1 = ws + 5 * MD;
  float* hid  = ws + 6 * MD;   // M x DINNER (32 MB) -> total ~82 MB

  cond_embed_kernel<<<dim3(NCOND, BATCH), 256, 0, stream>>>(
      conds, cW1, cb1, cW2, cb2, nullc, pos, x);
  tok_embed_kernel<<<dim3(S_TOK, BATCH), 256, 0, stream>>>(toks, emb, pos, x);

  dim3 g512(MROWS / 64, DMODEL / 64);
  dim3 g2048(MROWS / 64, DINNER / 64);

  for (int l = 0; l < NLAYER; l++) {
    const float* Wql = Wq + (size_t)l * DMODEL * DMODEL;
    const float* Wkl = Wk + (size_t)l * DMODEL * DMODEL;
    const float* Wvl = Wv + (size_t)l * DMODEL * DMODEL;
    const float* Wol = Wo + (size_t)l * DMODEL * DMODEL;

    gemm_kernel<<<g512, 256, 0, stream>>>(x, Wql, bq + l * DMODEL, nullptr,
        q, MROWS, DMODEL, DMODEL, 0, nullptr, nullptr, nullptr);
    gemm_kernel<<<g512, 256, 0, stream>>>(x, Wkl, bk + l * DMODEL, nullptr,
        k, MROWS, DMODEL, DMODEL, 0, nullptr, nullptr, nullptr);
    gemm_kernel<<<g512, 256, 0, stream>>>(x, Wvl, bv + l * DMODEL, nullptr,
        v, MROWS, DMODEL, DMODEL, 0, nullptr, nullptr, nullptr);

    attn_kernel<<<(BATCH * NHEAD * SEQ) / 4, 256, 0, stream>>>(
        q, k, v, E + (size_t)l * SEQ * DHEAD, toks, q);

    // t1 = attn @ Wo + bo + x (residual)
    gemm_kernel<<<g512, 256, 0, stream>>>(q, Wol, bo + l * DMODEL, x,
        t1, MROWS, DMODEL, DMODEL, 1, nullptr, nullptr, nullptr);
    ln_kernel<<<MROWS, 256, 0, stream>>>(t1, ln1g + l * DMODEL, ln1b + l * DMODEL, out1);

    // hid = relu(out1 @ W1 + b1) + chord
    gemm_kernel<<<g2048, 256, 0, stream>>>(out1, fW1 + (size_t)l * DMODEL * DINNER,
        fb1 + l * DINNER, nullptr, hid, MROWS, DINNER, DMODEL, 2,
        ttc, ttcW, ttcb);
    // t1 = hid @ W2 + b2 + out1
    gemm_kernel<<<g512, 256, 0, stream>>>(hid, fW2 + (size_t)l * DINNER * DMODEL,
        fb2 + l * DMODEL, out1, t1, MROWS, DMODEL, DINNER, 1,
        nullptr, nullptr, nullptr);
    ln_kernel<<<MROWS, 256, 0, stream>>>(t1, ln2g + l * DMODEL, ln2b + l * DMODEL, x);
  }

  // logits = x @ fc_W + fc_b
  gemm_kernel<<<dim3(MROWS / 64, VOCAB / 64), 256, 0, stream>>>(x, fcW, fcb, nullptr,
      (float*)d_out, MROWS, VOCAB, DMODEL, 0, nullptr, nullptr, nullptr);
}

// Round 3
// 8992.637 us; speedup vs baseline: 2.1071x; 2.1071x over previous
//
#include <hip/hip_runtime.h>
#include <hip/hip_bf16.h>
#include <math.h>

// ---- problem constants ----
#define BATCH  2
#define S_TOK  2046
#define NCOND  2
#define SEQ    2048
#define DMODEL 512
#define DINNER 2048
#define NHEAD  8
#define DHEAD  64
#define NLAYER 6
#define VOCAB  512
#define MROWS  (BATCH*SEQ)   // 4096 rows

typedef unsigned short bf16u;
__device__ __forceinline__ float b2f(bf16u u) {
  union { unsigned int i; float f; } v; v.i = ((unsigned int)u) << 16; return v.f;
}
__device__ __forceinline__ bf16u f2b(float f) {
  union { float f; unsigned int i; } v; v.f = f;
  unsigned int x = v.i;
  return (bf16u)((x + 0x7fffu + ((x >> 16) & 1u)) >> 16);
}

// ---------------------------------------------------------------------------
// Generic tiled GEMM: C[M,N] = A[M,K] @ W[K,N] + bias (fp32), fused epilogues.
// mode 0: +bias ; 1: +bias+R ; 2: relu(+bias)+chord
// 64x64 tile, BK=16, 256 threads, 4x4/thread, float4 LDS fragment reads.
// ---------------------------------------------------------------------------
__global__ __launch_bounds__(256) void gemm_kernel(
    const float* __restrict__ A, const float* __restrict__ W,
    const float* __restrict__ bias, const float* __restrict__ R,
    float* __restrict__ C,
    int M, int N, int K, int mode,
    const float* __restrict__ ttc, const float* __restrict__ ttcW,
    const float* __restrict__ ttcb)
{
  __shared__ float As[16][68];   // [k][m], 68-pad: 16B-aligned rows, no conflicts
  __shared__ float Ws[16][68];   // [k][n]
  const int tid = threadIdx.x;
  const int tn = tid & 15, tm = tid >> 4;
  const int row0 = blockIdx.x * 64, col0 = blockIdx.y * 64;
  float acc[4][4] = {};

  for (int k0 = 0; k0 < K; k0 += 16) {
#pragma unroll
    for (int i = 0; i < 4; i++) {
      int li = tid + i * 256;
      int r = li >> 4, c = li & 15;
      As[c][r] = A[(size_t)(row0 + r) * K + (k0 + c)];
    }
#pragma unroll
    for (int i = 0; i < 4; i++) {
      int li = tid + i * 256;
      int r = li >> 6, c = li & 63;
      Ws[r][c] = W[(size_t)(k0 + r) * N + (col0 + c)];
    }
    __syncthreads();
#pragma unroll
    for (int k = 0; k < 16; k++) {
      float4 av = *(const float4*)&As[k][tm * 4];
      float4 wv = *(const float4*)&Ws[k][tn * 4];
      float a[4] = {av.x, av.y, av.z, av.w};
      float w[4] = {wv.x, wv.y, wv.z, wv.w};
#pragma unroll
      for (int ii = 0; ii < 4; ii++)
#pragma unroll
        for (int jj = 0; jj < 4; jj++)
          acc[ii][jj] = fmaf(a[ii], w[jj], acc[ii][jj]);
    }
    __syncthreads();
  }

#pragma unroll
  for (int ii = 0; ii < 4; ii++) {
    int m = row0 + tm * 4 + ii;
    float tval = 0.f;
    if (mode == 2) {           // chord scalar for this row
      int b = m >> 11, s = m & (SEQ - 1);
      int sp = (s < NCOND) ? 0 : (s - NCOND);
      tval = 8.0f - ttc[b * S_TOK + sp];
    }
#pragma unroll
    for (int jj = 0; jj < 4; jj++) {
      int n = col0 + tn * 4 + jj;
      float v = acc[ii][jj] + bias[n];
      if (mode == 1)      v += R[(size_t)m * N + n];
      else if (mode == 2) v = fmaxf(v, 0.f) + tval * ttcW[n] + ttcb[n];
      C[(size_t)m * N + n] = v;
    }
  }
}

// ---------------------------------------------------------------------------
// LayerNorm over D=512, one row per block.
// ---------------------------------------------------------------------------
__global__ __launch_bounds__(256) void ln_kernel(
    const float* __restrict__ X, const float* __restrict__ g,
    const float* __restrict__ bta, float* __restrict__ Y)
{
  int row = blockIdx.x, tid = threadIdx.x;
  const float* xr = X + (size_t)row * DMODEL;
  float x0 = xr[tid], x1 = xr[tid + 256];
  __shared__ float red[8];
  int wv = tid >> 6, ln = tid & 63;
  float s = x0 + x1;
  for (int off = 32; off; off >>= 1) s += __shfl_xor(s, off);
  if (ln == 0) red[wv] = s;
  __syncthreads();
  float mu = (red[0] + red[1] + red[2] + red[3]) * (1.0f / DMODEL);
  float d0 = x0 - mu, d1 = x1 - mu;
  float vs = d0 * d0 + d1 * d1;
  for (int off = 32; off; off >>= 1) vs += __shfl_xor(vs, off);
  if (ln == 0) red[4 + wv] = vs;
  __syncthreads();
  float var = (red[4] + red[5] + red[6] + red[7]) * (1.0f / DMODEL);
  float rstd = rsqrtf(var + 1e-6f);
  Y[(size_t)row * DMODEL + tid]       = d0 * rstd * g[tid]       + bta[tid];
  Y[(size_t)row * DMODEL + tid + 256] = d1 * rstd * g[tid + 256] + bta[tid + 256];
}

// ---------------------------------------------------------------------------
__global__ __launch_bounds__(256) void tok_embed_kernel(
    const int* __restrict__ toks, const float* __restrict__ emb,
    const float* __restrict__ pos, float* __restrict__ x)
{
  int sp = blockIdx.x, b = blockIdx.y;
  int s = sp + NCOND;
  int tok = toks[b * S_TOK + sp];
  const float* er = emb + (size_t)tok * DMODEL;
  const float* pr = pos + (size_t)s * DMODEL;
  float* xr = x + ((size_t)b * SEQ + s) * DMODEL;
  for (int d = threadIdx.x; d < DMODEL; d += 256)
    xr[d] = er[d] * 22.62741699796952f + pr[d];   // sqrt(512)
}

// ---------------------------------------------------------------------------
__global__ __launch_bounds__(256) void cond_embed_kernel(
    const float* __restrict__ conds, const float* __restrict__ W1,
    const float* __restrict__ b1, const float* __restrict__ W2w,
    const float* __restrict__ b2, const float* __restrict__ nullc,
    const float* __restrict__ pos, float* __restrict__ x)
{
  int ci = blockIdx.x, b = blockIdx.y, tid = threadIdx.x;
  float c = conds[b * NCOND + ci];
  bool cn = isnan(c);
  float cm = cn ? 0.f : c;
  __shared__ float h1[DMODEL / 2];
  h1[tid] = fmaxf(cm * W1[ci * (DMODEL/2) + tid] + b1[ci * (DMODEL/2) + tid], 0.f);
  __syncthreads();
  for (int d = tid; d < DMODEL; d += 256) {
    float acc = b2[ci * DMODEL + d];
    for (int i = 0; i < DMODEL / 2; i++)
      acc = fmaf(h1[i], W2w[((size_t)ci * (DMODEL/2) + i) * DMODEL + d], acc);
    float ce = cn ? nullc[ci * DMODEL + d] : acc;
    x[((size_t)b * SEQ + ci) * DMODEL + d] = ce + pos[(size_t)ci * DMODEL + d];
  }
}

// ---------------------------------------------------------------------------
// Block-tiled flash attention. Block = 64 query rows of one (b,h), 256 thr.
// Thread (r = tid>>2, qd = tid&3): owns query row i0+r; computes 16 of 64
// scores per step (jl = 4*jj+qd); owns output d-chunk [16*qd, 16*qd+16).
// score(i,j) = q_i.(k_j + E[SEQ-1-i+j])/8, causal + key-pad masked.
// E-band per step: me = m0 + (jl - r + 63), m0 = SEQ-64-i0+j0, 128 rows (bf16).
// O aliases Q (each block's write set == its own private read slice).
// ---------------------------------------------------------------------------
__global__ __launch_bounds__(256) void attn_kernel(
    const float* Q, const float* __restrict__ K, const float* __restrict__ V,
    const float* __restrict__ E_l, const int* __restrict__ toks, float* O)
{
  __shared__ float Ks[64][68];
  __shared__ float Vs[64][68];
  __shared__ bf16u Es[128][68];
  __shared__ float Ps[64][68];   // also Q-tile staging scratch
  __shared__ float padv[64];

  const int tid = threadIdx.x;
  const int r = tid >> 2, qd = tid & 3;

  // block swizzle: interleave short/long i-tiles within each (b,h)
  int bid = blockIdx.x;
  int g = bid >> 5;              // 0..15 -> (b,h)
  int w = bid & 31;
  int it = (w & 1) ? (31 - (w >> 1)) : (w >> 1);
  int b = g >> 3, h = g & 7;
  const int i0 = it * 64;
  const int i = i0 + r;

  // ---- stage Q-tile via Ps, pull own row into registers ----
#pragma unroll
  for (int e = 0; e < 16; e++) {
    int idx = tid + e * 256;
    int r2 = idx >> 6, d = idx & 63;
    Ps[r2][d] = Q[((size_t)(b * SEQ + i0 + r2)) * DMODEL + h * DHEAD + d];
  }
  __syncthreads();
  float q[64];
#pragma unroll
  for (int d4 = 0; d4 < 16; d4++) {
    float4 t = *(const float4*)&Ps[r][d4 * 4];
    q[d4*4+0] = t.x; q[d4*4+1] = t.y; q[d4*4+2] = t.z; q[d4*4+3] = t.w;
  }

  float m_run = -1e30f, l_run = 0.f;
  float acc[16] = {};

  const int nst = it + 1;
  for (int js = 0; js < nst; js++) {
    const int j0 = js * 64;
    __syncthreads();   // prev PV (Ps,Vs) + Q staging done before overwrite

    // ---- stage K, V tiles (coalesced) ----
#pragma unroll
    for (int e = 0; e < 16; e++) {
      int idx = tid + e * 256;
      int jr = idx >> 6, d = idx & 63;
      size_t gi = ((size_t)(b * SEQ + j0 + jr)) * DMODEL + h * DHEAD + d;
      Ks[jr][d] = K[gi];
      Vs[jr][d] = V[gi];
    }
    // ---- stage E band (bf16), clamp unused tail rows ----
    const int m0 = SEQ - 64 - i0 + j0;
#pragma unroll
    for (int e = 0; e < 32; e++) {
      int idx = tid + e * 256;
      int er = idx >> 6, d = idx & 63;
      int row = m0 + er; if (row > SEQ - 1) row = SEQ - 1;
      Es[er][d] = f2b(E_l[(size_t)row * DHEAD + d]);
    }
    // ---- key-pad mask for this tile ----
    if (tid < 64) {
      int j = j0 + tid;
      bool pad = (j >= NCOND) && (toks[b * S_TOK + j - NCOND] == 0);
      padv[tid] = pad ? -1e30f : 0.f;
    }
    __syncthreads();

    // ---- QK + E scores: 16 per thread ----
    float sj[16];
#pragma unroll
    for (int jj = 0; jj < 16; jj++) {
      const int jl = 4 * jj + qd;
      const int eoff = jl - r + 63;
      const float4*  kp = (const float4*) &Ks[jl][0];
      const ushort4* ep = (const ushort4*)&Es[eoff][0];
      float s = 0.f;
#pragma unroll
      for (int d4 = 0; d4 < 16; d4++) {
        float4  kv = kp[d4];
        ushort4 ev = ep[d4];
        s = fmaf(q[d4*4+0], kv.x + b2f(ev.x), s);
        s = fmaf(q[d4*4+1], kv.y + b2f(ev.y), s);
        s = fmaf(q[d4*4+2], kv.z + b2f(ev.z), s);
        s = fmaf(q[d4*4+3], kv.w + b2f(ev.w), s);
      }
      s = s * 0.125f + padv[jl];
      if (j0 + jl > i) s = -1e30f;     // causal
      sj[jj] = s;
    }

    // ---- online softmax (row stats across the 4 qd-lanes) ----
    float mloc = sj[0];
#pragma unroll
    for (int jj = 1; jj < 16; jj++) mloc = fmaxf(mloc, sj[jj]);
    mloc = fmaxf(mloc, __shfl_xor(mloc, 1));
    mloc = fmaxf(mloc, __shfl_xor(mloc, 2));
    float m_new = fmaxf(m_run, mloc);
    float alpha = __expf(m_run - m_new);
    float psum = 0.f;
#pragma unroll
    for (int jj = 0; jj < 16; jj++) {
      float p = __expf(sj[jj] - m_new);
      Ps[r][4 * jj + qd] = p;
      psum += p;
    }
    psum += __shfl_xor(psum, 1);
    psum += __shfl_xor(psum, 2);
    l_run = l_run * alpha + psum;
    m_run = m_new;
#pragma unroll
    for (int t = 0; t < 16; t++) acc[t] *= alpha;
    __syncthreads();

    // ---- PV: accumulate own 16-dim chunk over all 64 keys ----
#pragma unroll 8
    for (int jl = 0; jl < 64; jl++) {
      float pv = Ps[r][jl];
      const float4* vp = (const float4*)&Vs[jl][qd * 16];
#pragma unroll
      for (int t4 = 0; t4 < 4; t4++) {
        float4 vv = vp[t4];
        acc[t4*4+0] = fmaf(pv, vv.x, acc[t4*4+0]);
        acc[t4*4+1] = fmaf(pv, vv.y, acc[t4*4+1]);
        acc[t4*4+2] = fmaf(pv, vv.z, acc[t4*4+2]);
        acc[t4*4+3] = fmaf(pv, vv.w, acc[t4*4+3]);
      }
    }
  }

  // ---- normalize + write (O aliases Q; safe per-block) ----
  float inv = 1.0f / l_run;
  float* ob = O + ((size_t)(b * SEQ + i)) * DMODEL + h * DHEAD + qd * 16;
#pragma unroll
  for (int t4 = 0; t4 < 4; t4++) {
    float4 ov;
    ov.x = acc[t4*4+0] * inv; ov.y = acc[t4*4+1] * inv;
    ov.z = acc[t4*4+2] * inv; ov.w = acc[t4*4+3] * inv;
    *(float4*)&ob[t4 * 4] = ov;
  }
}

// ---------------------------------------------------------------------------
extern "C" void kernel_launch(void* const* d_in, const int* in_sizes, int n_in,
                              void* d_out, int out_size, void* d_ws, size_t ws_size,
                              hipStream_t stream) {
  const int*   toks  = (const int*)  d_in[0];
  const float* conds = (const float*)d_in[1];
  const float* ttc   = (const float*)d_in[2];
  const float* emb   = (const float*)d_in[3];
  const float* pos   = (const float*)d_in[4];
  const float* cW1   = (const float*)d_in[5];
  const float* cb1   = (const float*)d_in[6];
  const float* cW2   = (const float*)d_in[7];
  const float* cb2   = (const float*)d_in[8];
  const float* nullc = (const float*)d_in[9];
  const float* ttcW  = (const float*)d_in[10];
  const float* ttcb  = (const float*)d_in[11];
  const float* Wq    = (const float*)d_in[12];
  const float* Wk    = (const float*)d_in[13];
  const float* Wv    = (const float*)d_in[14];
  const float* Wo    = (const float*)d_in[15];
  const float* bq    = (const float*)d_in[16];
  const float* bk    = (const float*)d_in[17];
  const float* bv    = (const float*)d_in[18];
  const float* bo    = (const float*)d_in[19];
  const float* E     = (const float*)d_in[20];
  const float* fW1   = (const float*)d_in[21];
  const float* fb1   = (const float*)d_in[22];
  const float* fW2   = (const float*)d_in[23];
  const float* fb2   = (const float*)d_in[24];
  const float* ln1g  = (const float*)d_in[25];
  const float* ln1b  = (const float*)d_in[26];
  const float* ln2g  = (const float*)d_in[27];
  const float* ln2b  = (const float*)d_in[28];
  const float* fcW   = (const float*)d_in[29];
  const float* fcb   = (const float*)d_in[30];

  float* ws = (float*)d_ws;
  const size_t MD = (size_t)MROWS * DMODEL;   // 8 MB
  float* x    = ws;
  float* q    = ws + 1 * MD;   // q, then attention output
  float* k    = ws + 2 * MD;
  float* v    = ws + 3 * MD;
  float* t1   = ws + 4 * MD;
  float* out1 = ws + 5 * MD;
  float* hid  = ws + 6 * MD;   // M x DINNER (32 MB)

  cond_embed_kernel<<<dim3(NCOND, BATCH), 256, 0, stream>>>(
      conds, cW1, cb1, cW2, cb2, nullc, pos, x);
  tok_embed_kernel<<<dim3(S_TOK, BATCH), 256, 0, stream>>>(toks, emb, pos, x);

  dim3 g512(MROWS / 64, DMODEL / 64);
  dim3 g2048(MROWS / 64, DINNER / 64);

  for (int l = 0; l < NLAYER; l++) {
    const float* Wql = Wq + (size_t)l * DMODEL * DMODEL;
    const float* Wkl = Wk + (size_t)l * DMODEL * DMODEL;
    const float* Wvl = Wv + (size_t)l * DMODEL * DMODEL;
    const float* Wol = Wo + (size_t)l * DMODEL * DMODEL;

    gemm_kernel<<<g512, 256, 0, stream>>>(x, Wql, bq + l * DMODEL, nullptr,
        q, MROWS, DMODEL, DMODEL, 0, nullptr, nullptr, nullptr);
    gemm_kernel<<<g512, 256, 0, stream>>>(x, Wkl, bk + l * DMODEL, nullptr,
        k, MROWS, DMODEL, DMODEL, 0, nullptr, nullptr, nullptr);
    gemm_kernel<<<g512, 256, 0, stream>>>(x, Wvl, bv + l * DMODEL, nullptr,
        v, MROWS, DMODEL, DMODEL, 0, nullptr, nullptr, nullptr);

    attn_kernel<<<BATCH * NHEAD * (SEQ / 64), 256, 0, stream>>>(
        q, k, v, E + (size_t)l * SEQ * DHEAD, toks, q);

    gemm_kernel<<<g512, 256, 0, stream>>>(q, Wol, bo + l * DMODEL, x,
        t1, MROWS, DMODEL, DMODEL, 1, nullptr, nullptr, nullptr);
    ln_kernel<<<MROWS, 256, 0, stream>>>(t1, ln1g + l * DMODEL, ln1b + l * DMODEL, out1);

    gemm_kernel<<<g2048, 256, 0, stream>>>(out1, fW1 + (size_t)l * DMODEL * DINNER,
        fb1 + l * DINNER, nullptr, hid, MROWS, DINNER, DMODEL, 2,
        ttc, ttcW, ttcb);
    gemm_kernel<<<g512, 256, 0, stream>>>(hid, fW2 + (size_t)l * DINNER * DMODEL,
        fb2 + l * DMODEL, out1, t1, MROWS, DMODEL, DINNER, 1,
        nullptr, nullptr, nullptr);
    ln_kernel<<<MROWS, 256, 0, stream>>>(t1, ln2g + l * DMODEL, ln2b + l * DMODEL, x);
  }

  gemm_kernel<<<dim3(MROWS / 64, VOCAB / 64), 256, 0, stream>>>(x, fcW, fcb, nullptr,
      (float*)d_out, MROWS, VOCAB, DMODEL, 0, nullptr, nullptr, nullptr);
}

// Round 4
// 3745.510 us; speedup vs baseline: 5.0590x; 2.4009x over previous
//
#include <hip/hip_runtime.h>
#include <hip/hip_bf16.h>
#include <math.h>

// ---- problem constants ----
#define BATCH  2
#define S_TOK  2046
#define NCOND  2
#define SEQ    2048
#define DMODEL 512
#define DINNER 2048
#define NHEAD  8
#define DHEAD  64
#define NLAYER 6
#define VOCAB  512
#define MROWS  (BATCH*SEQ)   // 4096 rows

typedef unsigned short bf16u;
typedef __attribute__((ext_vector_type(8))) short s8frag;   // 8 bf16 (4 VGPRs)
typedef __attribute__((ext_vector_type(4))) float f4frag;   // 4 fp32 acc

__device__ __forceinline__ float b2f(bf16u u) {
  union { unsigned int i; float f; } v; v.i = ((unsigned int)u) << 16; return v.f;
}
__device__ __forceinline__ bf16u f2b(float f) {
  union { float f; unsigned int i; } v; v.f = f;
  unsigned int x = v.i;
  return (bf16u)((x + 0x7fffu + ((x >> 16) & 1u)) >> 16);
}
__device__ __forceinline__ unsigned int pack2(float a, float b) {
  return (unsigned int)f2b(a) | ((unsigned int)f2b(b) << 16);
}

// ---------------------------------------------------------------------------
// Generic tiled GEMM (fp32 VALU): C = A@W + bias, fused epilogues.
// mode 0: +bias ; 1: +bias+R ; 2: relu(+bias)+chord
// ---------------------------------------------------------------------------
__global__ __launch_bounds__(256) void gemm_kernel(
    const float* __restrict__ A, const float* __restrict__ W,
    const float* __restrict__ bias, const float* __restrict__ R,
    float* __restrict__ C,
    int M, int N, int K, int mode,
    const float* __restrict__ ttc, const float* __restrict__ ttcW,
    const float* __restrict__ ttcb)
{
  __shared__ float As[16][68];
  __shared__ float Ws[16][68];
  const int tid = threadIdx.x;
  const int tn = tid & 15, tm = tid >> 4;
  const int row0 = blockIdx.x * 64, col0 = blockIdx.y * 64;
  float acc[4][4] = {};

  for (int k0 = 0; k0 < K; k0 += 16) {
#pragma unroll
    for (int i = 0; i < 4; i++) {
      int li = tid + i * 256;
      int r = li >> 4, c = li & 15;
      As[c][r] = A[(size_t)(row0 + r) * K + (k0 + c)];
    }
#pragma unroll
    for (int i = 0; i < 4; i++) {
      int li = tid + i * 256;
      int r = li >> 6, c = li & 63;
      Ws[r][c] = W[(size_t)(k0 + r) * N + (col0 + c)];
    }
    __syncthreads();
#pragma unroll
    for (int k = 0; k < 16; k++) {
      float4 av = *(const float4*)&As[k][tm * 4];
      float4 wv = *(const float4*)&Ws[k][tn * 4];
      float a[4] = {av.x, av.y, av.z, av.w};
      float w[4] = {wv.x, wv.y, wv.z, wv.w};
#pragma unroll
      for (int ii = 0; ii < 4; ii++)
#pragma unroll
        for (int jj = 0; jj < 4; jj++)
          acc[ii][jj] = fmaf(a[ii], w[jj], acc[ii][jj]);
    }
    __syncthreads();
  }

#pragma unroll
  for (int ii = 0; ii < 4; ii++) {
    int m = row0 + tm * 4 + ii;
    float tval = 0.f;
    if (mode == 2) {
      int b = m >> 11, s = m & (SEQ - 1);
      int sp = (s < NCOND) ? 0 : (s - NCOND);
      tval = 8.0f - ttc[b * S_TOK + sp];
    }
#pragma unroll
    for (int jj = 0; jj < 4; jj++) {
      int n = col0 + tn * 4 + jj;
      float v = acc[ii][jj] + bias[n];
      if (mode == 1)      v += R[(size_t)m * N + n];
      else if (mode == 2) v = fmaxf(v, 0.f) + tval * ttcW[n] + ttcb[n];
      C[(size_t)m * N + n] = v;
    }
  }
}

// ---------------------------------------------------------------------------
__global__ __launch_bounds__(256) void ln_kernel(
    const float* __restrict__ X, const float* __restrict__ g,
    const float* __restrict__ bta, float* __restrict__ Y)
{
  int row = blockIdx.x, tid = threadIdx.x;
  const float* xr = X + (size_t)row * DMODEL;
  float x0 = xr[tid], x1 = xr[tid + 256];
  __shared__ float red[8];
  int wv = tid >> 6, ln = tid & 63;
  float s = x0 + x1;
  for (int off = 32; off; off >>= 1) s += __shfl_xor(s, off);
  if (ln == 0) red[wv] = s;
  __syncthreads();
  float mu = (red[0] + red[1] + red[2] + red[3]) * (1.0f / DMODEL);
  float d0 = x0 - mu, d1 = x1 - mu;
  float vs = d0 * d0 + d1 * d1;
  for (int off = 32; off; off >>= 1) vs += __shfl_xor(vs, off);
  if (ln == 0) red[4 + wv] = vs;
  __syncthreads();
  float var = (red[4] + red[5] + red[6] + red[7]) * (1.0f / DMODEL);
  float rstd = rsqrtf(var + 1e-6f);
  Y[(size_t)row * DMODEL + tid]       = d0 * rstd * g[tid]       + bta[tid];
  Y[(size_t)row * DMODEL + tid + 256] = d1 * rstd * g[tid + 256] + bta[tid + 256];
}

// ---------------------------------------------------------------------------
__global__ __launch_bounds__(256) void tok_embed_kernel(
    const int* __restrict__ toks, const float* __restrict__ emb,
    const float* __restrict__ pos, float* __restrict__ x)
{
  int sp = blockIdx.x, b = blockIdx.y;
  int s = sp + NCOND;
  int tok = toks[b * S_TOK + sp];
  const float* er = emb + (size_t)tok * DMODEL;
  const float* pr = pos + (size_t)s * DMODEL;
  float* xr = x + ((size_t)b * SEQ + s) * DMODEL;
  for (int d = threadIdx.x; d < DMODEL; d += 256)
    xr[d] = er[d] * 22.62741699796952f + pr[d];   // sqrt(512)
}

// ---------------------------------------------------------------------------
__global__ __launch_bounds__(256) void cond_embed_kernel(
    const float* __restrict__ conds, const float* __restrict__ W1,
    const float* __restrict__ b1, const float* __restrict__ W2w,
    const float* __restrict__ b2, const float* __restrict__ nullc,
    const float* __restrict__ pos, float* __restrict__ x)
{
  int ci = blockIdx.x, b = blockIdx.y, tid = threadIdx.x;
  float c = conds[b * NCOND + ci];
  bool cn = isnan(c);
  float cm = cn ? 0.f : c;
  __shared__ float h1[DMODEL / 2];
  h1[tid] = fmaxf(cm * W1[ci * (DMODEL/2) + tid] + b1[ci * (DMODEL/2) + tid], 0.f);
  __syncthreads();
  for (int d = tid; d < DMODEL; d += 256) {
    float acc = b2[ci * DMODEL + d];
    for (int i = 0; i < DMODEL / 2; i++)
      acc = fmaf(h1[i], W2w[((size_t)ci * (DMODEL/2) + i) * DMODEL + d], acc);
    float ce = cn ? nullc[ci * DMODEL + d] : acc;
    x[((size_t)b * SEQ + ci) * DMODEL + d] = ce + pos[(size_t)ci * DMODEL + d];
  }
}

// ---------------------------------------------------------------------------
// E (fp32, one layer) -> bf16 scratch.
// ---------------------------------------------------------------------------
__global__ __launch_bounds__(256) void e_conv_kernel(
    const float* __restrict__ E, bf16u* __restrict__ Eb)
{
  int i = (blockIdx.x * 256 + threadIdx.x) * 4;   // SEQ*DHEAD = 131072 elems
  float4 v = *(const float4*)&E[i];
  ushort4 o;
  o.x = f2b(v.x); o.y = f2b(v.y); o.z = f2b(v.z); o.w = f2b(v.w);
  *(ushort4*)&Eb[i] = o;
}

// ---------------------------------------------------------------------------
// MFMA flash attention. Block = 64 Q-rows of one (b,h); 4 waves x 16 rows.
// score(i,j) = [q_i.k_j + q_i.E(2047-i+j)]/8 + mask. 16x16x32 bf16 MFMA.
// Layouts (m89/m120 verified): A/B frag [m=lane&15][k=quad*8+j];
// C/D [row=quad*4+reg][col=lane&15].
// O aliases Q buffer (block reads only its own rows, at block start).
// ---------------------------------------------------------------------------
__global__ __launch_bounds__(256) void attn_kernel(
    const float* Q, const float* __restrict__ K, const float* __restrict__ V,
    const bf16u* __restrict__ Eb16, const int* __restrict__ toks, float* O)
{
  __shared__ bf16u Kb[64][72];     // K[key][d]
  __shared__ bf16u Vt[64][72];     // V^T[d][key]
  __shared__ bf16u Ebs[128][72];   // E band [mm][d]
  __shared__ bf16u Ps[64][72];     // P[row][key] (per-wave 16-row slices)
  __shared__ bf16u QEs[64][136];   // QE band [row][mm]
  __shared__ float padv[64];

  const int tid  = threadIdx.x;
  const int lane = tid & 63;
  const int wave = tid >> 6;
  const int quad = lane >> 4;
  const int l16  = lane & 15;

  int bid = blockIdx.x;
  int g = bid >> 5;                // (b,h)
  int w = bid & 31;
  int it = (w & 1) ? (31 - (w >> 1)) : (w >> 1);
  int b = g >> 3, h = g & 7;
  const int i0 = it * 64;

  // ---- Q A-frags (own rows, direct from global, 2 k-chunks) ----
  s8frag q0, q1;
  {
    const float* qr = Q + ((size_t)(b * SEQ + i0 + wave * 16 + l16)) * DMODEL
                        + h * DHEAD + quad * 8;
#pragma unroll
    for (int j = 0; j < 8; j++) q0[j] = (short)f2b(qr[j]);
#pragma unroll
    for (int j = 0; j < 8; j++) q1[j] = (short)f2b(qr[32 + j]);
  }

  float m_run[4], l_run[4];
  f4frag acc[4];
#pragma unroll
  for (int r = 0; r < 4; r++) { m_run[r] = -1e30f; l_run[r] = 0.f; }
#pragma unroll
  for (int dt = 0; dt < 4; dt++) acc[dt] = (f4frag){0.f, 0.f, 0.f, 0.f};

  const int nst = it + 1;
  for (int js = 0; js < nst; js++) {
    const int j0 = js * 64;
    __syncthreads();   // previous iteration's LDS reads complete

    // ---- stage K tile (bf16, packed uint writes) ----
#pragma unroll
    for (int e = 0; e < 8; e++) {
      int idx = e * 256 + tid;
      int jr = idx >> 5, dp = (idx & 31) * 2;
      const float* kp = K + ((size_t)(b * SEQ + j0 + jr)) * DMODEL + h * DHEAD + dp;
      *(unsigned int*)&Kb[jr][dp] = pack2(kp[0], kp[1]);
    }
    // ---- stage V transposed: Vt[d][j] ----
#pragma unroll
    for (int e = 0; e < 8; e++) {
      int idx = e * 256 + tid;
      int d = idx & 63, jp = idx >> 6;   // jp 0..31
      size_t g0 = ((size_t)(b * SEQ + j0 + 2 * jp)) * DMODEL + h * DHEAD + d;
      *(unsigned int*)&Vt[d][2 * jp] = pack2(V[g0], V[g0 + DMODEL]);
    }
    // ---- stage E band (already bf16): rows m0..m0+127, clamped ----
    const int m0 = SEQ - 64 - i0 + j0;
#pragma unroll
    for (int e = 0; e < 16; e++) {
      int idx = e * 256 + tid;
      int er = idx >> 5, dp = (idx & 31) * 2;
      int row = m0 + er; if (row > SEQ - 1) row = SEQ - 1;
      *(unsigned int*)&Ebs[er][dp] = *(const unsigned int*)&Eb16[(size_t)row * DHEAD + dp];
    }
    if (tid < 64) {
      int j = j0 + tid;
      bool pad = (j >= NCOND) && (toks[b * S_TOK + j - NCOND] == 0);
      padv[tid] = pad ? -1e30f : 0.f;
    }
    __syncthreads();

    // ---- QK^T: sc[nt] over 4 key-subtiles ----
    f4frag sc[4];
#pragma unroll
    for (int nt = 0; nt < 4; nt++) {
      s8frag k0 = *(const s8frag*)&Kb[nt * 16 + l16][quad * 8];
      s8frag k1 = *(const s8frag*)&Kb[nt * 16 + l16][32 + quad * 8];
      f4frag c = (f4frag){0.f, 0.f, 0.f, 0.f};
      c = __builtin_amdgcn_mfma_f32_16x16x32_bf16(q0, k0, c, 0, 0, 0);
      c = __builtin_amdgcn_mfma_f32_16x16x32_bf16(q1, k1, c, 0, 0, 0);
      sc[nt] = c;
    }

    // ---- Q.E band (128 cols) -> QEs LDS (own wave rows) ----
#pragma unroll
    for (int ct = 0; ct < 8; ct++) {
      s8frag e0 = *(const s8frag*)&Ebs[ct * 16 + l16][quad * 8];
      s8frag e1 = *(const s8frag*)&Ebs[ct * 16 + l16][32 + quad * 8];
      f4frag c = (f4frag){0.f, 0.f, 0.f, 0.f};
      c = __builtin_amdgcn_mfma_f32_16x16x32_bf16(q0, e0, c, 0, 0, 0);
      c = __builtin_amdgcn_mfma_f32_16x16x32_bf16(q1, e1, c, 0, 0, 0);
#pragma unroll
      for (int r = 0; r < 4; r++)
        QEs[wave * 16 + quad * 4 + r][ct * 16 + l16] = f2b(c[r]);
    }

    // ---- scores + online softmax (C layout; row = quad*4+reg) ----
    float s[4][4], mx[4];
#pragma unroll
    for (int r = 0; r < 4; r++) {
      int rloc = wave * 16 + quad * 4 + r;      // row in 64-block
      int ig = i0 + rloc;
#pragma unroll
      for (int nt = 0; nt < 4; nt++) {
        int jl = nt * 16 + l16;
        float qe = b2f(QEs[rloc][63 + jl - rloc]);
        float sv = (sc[nt][r] + qe) * 0.125f + padv[jl];
        if (j0 + jl > ig) sv = -1e30f;
        s[nt][r] = sv;
      }
      float m = fmaxf(fmaxf(s[0][r], s[1][r]), fmaxf(s[2][r], s[3][r]));
      m = fmaxf(m, __shfl_xor(m, 1));
      m = fmaxf(m, __shfl_xor(m, 2));
      m = fmaxf(m, __shfl_xor(m, 4));
      m = fmaxf(m, __shfl_xor(m, 8));
      mx[r] = m;
    }
    float alpha[4];
#pragma unroll
    for (int r = 0; r < 4; r++) {
      float m_new = fmaxf(m_run[r], mx[r]);
      alpha[r] = __expf(m_run[r] - m_new);
      float psum = 0.f;
      int rloc = wave * 16 + quad * 4 + r;
#pragma unroll
      for (int nt = 0; nt < 4; nt++) {
        float p = __expf(s[nt][r] - m_new);
        Ps[rloc][nt * 16 + l16] = f2b(p);
        psum += p;
      }
      psum += __shfl_xor(psum, 1);
      psum += __shfl_xor(psum, 2);
      psum += __shfl_xor(psum, 4);
      psum += __shfl_xor(psum, 8);
      l_run[r] = l_run[r] * alpha[r] + psum;
      m_run[r] = m_new;
    }
#pragma unroll
    for (int dt = 0; dt < 4; dt++)
#pragma unroll
      for (int r = 0; r < 4; r++) acc[dt][r] *= alpha[r];

    // ---- P @ V ----
    s8frag p0 = *(const s8frag*)&Ps[wave * 16 + l16][quad * 8];
    s8frag p1 = *(const s8frag*)&Ps[wave * 16 + l16][32 + quad * 8];
#pragma unroll
    for (int dt = 0; dt < 4; dt++) {
      s8frag v0 = *(const s8frag*)&Vt[dt * 16 + l16][quad * 8];
      s8frag v1 = *(const s8frag*)&Vt[dt * 16 + l16][32 + quad * 8];
      acc[dt] = __builtin_amdgcn_mfma_f32_16x16x32_bf16(p0, v0, acc[dt], 0, 0, 0);
      acc[dt] = __builtin_amdgcn_mfma_f32_16x16x32_bf16(p1, v1, acc[dt], 0, 0, 0);
    }
  }

  // ---- normalize + write (O aliases Q; block-private rows) ----
#pragma unroll
  for (int r = 0; r < 4; r++) {
    float inv = 1.0f / l_run[r];
    int ig = i0 + wave * 16 + quad * 4 + r;
    float* ob = O + ((size_t)(b * SEQ + ig)) * DMODEL + h * DHEAD;
#pragma unroll
    for (int dt = 0; dt < 4; dt++)
      ob[dt * 16 + l16] = acc[dt][r] * inv;
  }
}

// ---------------------------------------------------------------------------
extern "C" void kernel_launch(void* const* d_in, const int* in_sizes, int n_in,
                              void* d_out, int out_size, void* d_ws, size_t ws_size,
                              hipStream_t stream) {
  const int*   toks  = (const int*)  d_in[0];
  const float* conds = (const float*)d_in[1];
  const float* ttc   = (const float*)d_in[2];
  const float* emb   = (const float*)d_in[3];
  const float* pos   = (const float*)d_in[4];
  const float* cW1   = (const float*)d_in[5];
  const float* cb1   = (const float*)d_in[6];
  const float* cW2   = (const float*)d_in[7];
  const float* cb2   = (const float*)d_in[8];
  const float* nullc = (const float*)d_in[9];
  const float* ttcW  = (const float*)d_in[10];
  const float* ttcb  = (const float*)d_in[11];
  const float* Wq    = (const float*)d_in[12];
  const float* Wk    = (const float*)d_in[13];
  const float* Wv    = (const float*)d_in[14];
  const float* Wo    = (const float*)d_in[15];
  const float* bq    = (const float*)d_in[16];
  const float* bk    = (const float*)d_in[17];
  const float* bv    = (const float*)d_in[18];
  const float* bo    = (const float*)d_in[19];
  const float* E     = (const float*)d_in[20];
  const float* fW1   = (const float*)d_in[21];
  const float* fb1   = (const float*)d_in[22];
  const float* fW2   = (const float*)d_in[23];
  const float* fb2   = (const float*)d_in[24];
  const float* ln1g  = (const float*)d_in[25];
  const float* ln1b  = (const float*)d_in[26];
  const float* ln2g  = (const float*)d_in[27];
  const float* ln2b  = (const float*)d_in[28];
  const float* fcW   = (const float*)d_in[29];
  const float* fcb   = (const float*)d_in[30];

  float* ws = (float*)d_ws;
  const size_t MD = (size_t)MROWS * DMODEL;   // 8 MB
  float* x    = ws;
  float* q    = ws + 1 * MD;   // q, then attention output
  float* k    = ws + 2 * MD;
  float* v    = ws + 3 * MD;
  float* t1   = ws + 4 * MD;
  float* out1 = ws + 5 * MD;
  float* hid  = ws + 6 * MD;   // M x DINNER (32 MB) -> 80 MB total
  bf16u* ebf  = (bf16u*)out1;  // E bf16 scratch: free until ln1 of same layer

  cond_embed_kernel<<<dim3(NCOND, BATCH), 256, 0, stream>>>(
      conds, cW1, cb1, cW2, cb2, nullc, pos, x);
  tok_embed_kernel<<<dim3(S_TOK, BATCH), 256, 0, stream>>>(toks, emb, pos, x);

  dim3 g512(MROWS / 64, DMODEL / 64);
  dim3 g2048(MROWS / 64, DINNER / 64);

  for (int l = 0; l < NLAYER; l++) {
    const float* Wql = Wq + (size_t)l * DMODEL * DMODEL;
    const float* Wkl = Wk + (size_t)l * DMODEL * DMODEL;
    const float* Wvl = Wv + (size_t)l * DMODEL * DMODEL;
    const float* Wol = Wo + (size_t)l * DMODEL * DMODEL;

    gemm_kernel<<<g512, 256, 0, stream>>>(x, Wql, bq + l * DMODEL, nullptr,
        q, MROWS, DMODEL, DMODEL, 0, nullptr, nullptr, nullptr);
    gemm_kernel<<<g512, 256, 0, stream>>>(x, Wkl, bk + l * DMODEL, nullptr,
        k, MROWS, DMODEL, DMODEL, 0, nullptr, nullptr, nullptr);
    gemm_kernel<<<g512, 256, 0, stream>>>(x, Wvl, bv + l * DMODEL, nullptr,
        v, MROWS, DMODEL, DMODEL, 0, nullptr, nullptr, nullptr);

    e_conv_kernel<<<(SEQ * DHEAD) / 1024, 256, 0, stream>>>(
        E + (size_t)l * SEQ * DHEAD, ebf);
    attn_kernel<<<BATCH * NHEAD * (SEQ / 64), 256, 0, stream>>>(
        q, k, v, ebf, toks, q);

    gemm_kernel<<<g512, 256, 0, stream>>>(q, Wol, bo + l * DMODEL, x,
        t1, MROWS, DMODEL, DMODEL, 1, nullptr, nullptr, nullptr);
    ln_kernel<<<MROWS, 256, 0, stream>>>(t1, ln1g + l * DMODEL, ln1b + l * DMODEL, out1);

    gemm_kernel<<<g2048, 256, 0, stream>>>(out1, fW1 + (size_t)l * DMODEL * DINNER,
        fb1 + l * DINNER, nullptr, hid, MROWS, DINNER, DMODEL, 2,
        ttc, ttcW, ttcb);
    gemm_kernel<<<g512, 256, 0, stream>>>(hid, fW2 + (size_t)l * DINNER * DMODEL,
        fb2 + l * DMODEL, out1, t1, MROWS, DMODEL, DINNER, 1,
        nullptr, nullptr, nullptr);
    ln_kernel<<<MROWS, 256, 0, stream>>>(t1, ln2g + l * DMODEL, ln2b + l * DMODEL, x);
  }

  gemm_kernel<<<dim3(MROWS / 64, VOCAB / 64), 256, 0, stream>>>(x, fcW, fcb, nullptr,
      (float*)d_out, MROWS, VOCAB, DMODEL, 0, nullptr, nullptr, nullptr);
}

// Round 5
// 2103.018 us; speedup vs baseline: 9.0102x; 1.7810x over previous
//
#include <hip/hip_runtime.h>
#include <hip/hip_bf16.h>
#include <math.h>

// ---- problem constants ----
#define BATCH  2
#define S_TOK  2046
#define NCOND  2
#define SEQ    2048
#define DMODEL 512
#define DINNER 2048
#define NHEAD  8
#define DHEAD  64
#define NLAYER 6
#define VOCAB  512
#define MROWS  (BATCH*SEQ)   // 4096 rows

typedef unsigned short bf16u;
typedef __attribute__((ext_vector_type(8))) short s8frag;   // 8 bf16 (4 VGPRs)
typedef __attribute__((ext_vector_type(4))) float f4frag;   // 4 fp32 acc

__device__ __forceinline__ float b2f(bf16u u) {
  union { unsigned int i; float f; } v; v.i = ((unsigned int)u) << 16; return v.f;
}
__device__ __forceinline__ bf16u f2b(float f) {
  union { float f; unsigned int i; } v; v.f = f;
  unsigned int x = v.i;
  return (bf16u)((x + 0x7fffu + ((x >> 16) & 1u)) >> 16);
}

// ---------------------------------------------------------------------------
// Weight transpose + bf16 convert: dst[N][K] (bf16) = src[K][N] (fp32).
// One launch per layer: 768 blocks = 4x64 (Wq..Wo 512x512) + 256 (W1 512x2048)
// + 256 (W2 2048x512). 64x64 tile per block via padded LDS.
// ---------------------------------------------------------------------------
__global__ __launch_bounds__(256) void wt_kernel(
    const float* __restrict__ Wq, const float* __restrict__ Wk,
    const float* __restrict__ Wv, const float* __restrict__ Wo,
    const float* __restrict__ W1, const float* __restrict__ W2,
    bf16u* __restrict__ qT, bf16u* __restrict__ kT,
    bf16u* __restrict__ vT, bf16u* __restrict__ oT,
    bf16u* __restrict__ w1T, bf16u* __restrict__ w2T, int layer)
{
  int bid = blockIdx.x;
  const float* src; bf16u* dst; int K, N, kt, nt;
  if (bid < 256) {
    int mat = bid >> 6, t = bid & 63;
    const float* s4[4] = {Wq, Wk, Wv, Wo};
    bf16u*       d4[4] = {qT, kT, vT, oT};
    src = s4[mat] + (size_t)layer * DMODEL * DMODEL; dst = d4[mat];
    K = DMODEL; N = DMODEL; kt = t >> 3; nt = t & 7;
  } else if (bid < 512) {
    int t = bid - 256;
    src = W1 + (size_t)layer * DMODEL * DINNER; dst = w1T;
    K = DMODEL; N = DINNER; kt = t >> 5; nt = t & 31;
  } else {
    int t = bid - 512;
    src = W2 + (size_t)layer * DINNER * DMODEL; dst = w2T;
    K = DINNER; N = DMODEL; kt = t >> 3; nt = t & 7;
  }
  __shared__ bf16u Ls[64][66];
  int tid = threadIdx.x;
  int c = tid & 63, r4 = tid >> 6;
#pragma unroll
  for (int i = 0; i < 16; i++) {
    int r = i * 4 + r4;
    Ls[r][c] = f2b(src[(size_t)(kt * 64 + r) * N + nt * 64 + c]);
  }
  __syncthreads();
#pragma unroll
  for (int i = 0; i < 16; i++) {
    int rr = i * 4 + r4;   // n within tile
    dst[(size_t)(nt * 64 + rr) * K + kt * 64 + c] = Ls[c][rr];
  }
}

// ---------------------------------------------------------------------------
// MFMA GEMM: C[M,N] = A[M,K](bf16) @ Wt[N,K](bf16)^T + bias, fused epilogues.
// 128x128 tile, BK=32, 4 waves (2x2), each wave 64x64 via 4x4 16x16x32 MFMAs.
// A/B frag [m=lane&15][k=quad*8+j]; C/D [row=quad*4+reg][col=lane&15].
// mode 0: +bias -> bf16 ; 1: +bias+R -> fp32 ; 2: relu(+bias)+chord -> bf16 ;
// mode 3: +bias -> fp32
// ---------------------------------------------------------------------------
__global__ __launch_bounds__(256) void mgemm(
    const bf16u* __restrict__ A, const bf16u* __restrict__ Wt,
    const float* __restrict__ bias, const float* __restrict__ R,
    float* __restrict__ Cf, bf16u* __restrict__ Cb,
    int M, int N, int K, int mode,
    const float* __restrict__ ttc, const float* __restrict__ ttcW,
    const float* __restrict__ ttcb)
{
  __shared__ bf16u Ab[128][40];   // pad 40: 16B-aligned rows, ~2-way banks
  __shared__ bf16u Bb[128][40];
  const int tid = threadIdx.x;
  const int lane = tid & 63, wave = tid >> 6;
  const int quad = lane >> 4, l16 = lane & 15;
  const int wm = wave >> 1, wn = wave & 1;
  const int row0 = blockIdx.x * 128, col0 = blockIdx.y * 128;

  f4frag acc[4][4];
#pragma unroll
  for (int i = 0; i < 4; i++)
#pragma unroll
    for (int j = 0; j < 4; j++) acc[i][j] = (f4frag){0.f, 0.f, 0.f, 0.f};

  for (int k0 = 0; k0 < K; k0 += 32) {
    if (k0) __syncthreads();
#pragma unroll
    for (int i = 0; i < 2; i++) {
      int c = tid + i * 256;
      int r = c >> 2, koff = (c & 3) * 8;
      *(uint4*)&Ab[r][koff] = *(const uint4*)&A [(size_t)(row0 + r) * K + k0 + koff];
      *(uint4*)&Bb[r][koff] = *(const uint4*)&Wt[(size_t)(col0 + r) * K + k0 + koff];
    }
    __syncthreads();
    s8frag af[4], bfr[4];
#pragma unroll
    for (int t = 0; t < 4; t++) {
      af [t] = *(const s8frag*)&Ab[wm * 64 + t * 16 + l16][quad * 8];
      bfr[t] = *(const s8frag*)&Bb[wn * 64 + t * 16 + l16][quad * 8];
    }
#pragma unroll
    for (int mt = 0; mt < 4; mt++)
#pragma unroll
      for (int nt = 0; nt < 4; nt++)
        acc[mt][nt] = __builtin_amdgcn_mfma_f32_16x16x32_bf16(
            af[mt], bfr[nt], acc[mt][nt], 0, 0, 0);
  }

#pragma unroll
  for (int mt = 0; mt < 4; mt++) {
#pragma unroll
    for (int r = 0; r < 4; r++) {
      int m = row0 + wm * 64 + mt * 16 + quad * 4 + r;
      float tval = 0.f;
      if (mode == 2) {
        int b = m >> 11, s = m & (SEQ - 1);
        int sp = (s < NCOND) ? 0 : (s - NCOND);
        tval = 8.0f - ttc[b * S_TOK + sp];
      }
#pragma unroll
      for (int nt = 0; nt < 4; nt++) {
        int n = col0 + wn * 64 + nt * 16 + l16;
        float v = acc[mt][nt][r] + bias[n];
        if (mode == 1)      v += R[(size_t)m * N + n];
        else if (mode == 2) v = fmaxf(v, 0.f) + tval * ttcW[n] + ttcb[n];
        if (mode == 0 || mode == 2) Cb[(size_t)m * N + n] = f2b(v);
        else                        Cf[(size_t)m * N + n] = v;
      }
    }
  }
}

// ---------------------------------------------------------------------------
// LayerNorm over D=512; writes fp32 Y (residual stream) + bf16 Yb (GEMM A).
// ---------------------------------------------------------------------------
__global__ __launch_bounds__(256) void ln_kernel(
    const float* __restrict__ X, const float* __restrict__ g,
    const float* __restrict__ bta, float* __restrict__ Y, bf16u* __restrict__ Yb)
{
  int row = blockIdx.x, tid = threadIdx.x;
  const float* xr = X + (size_t)row * DMODEL;
  float x0 = xr[tid], x1 = xr[tid + 256];
  __shared__ float red[8];
  int wv = tid >> 6, ln = tid & 63;
  float s = x0 + x1;
  for (int off = 32; off; off >>= 1) s += __shfl_xor(s, off);
  if (ln == 0) red[wv] = s;
  __syncthreads();
  float mu = (red[0] + red[1] + red[2] + red[3]) * (1.0f / DMODEL);
  float d0 = x0 - mu, d1 = x1 - mu;
  float vs = d0 * d0 + d1 * d1;
  for (int off = 32; off; off >>= 1) vs += __shfl_xor(vs, off);
  if (ln == 0) red[4 + wv] = vs;
  __syncthreads();
  float var = (red[4] + red[5] + red[6] + red[7]) * (1.0f / DMODEL);
  float rstd = rsqrtf(var + 1e-6f);
  float y0 = d0 * rstd * g[tid]       + bta[tid];
  float y1 = d1 * rstd * g[tid + 256] + bta[tid + 256];
  Y [(size_t)row * DMODEL + tid]       = y0;
  Y [(size_t)row * DMODEL + tid + 256] = y1;
  Yb[(size_t)row * DMODEL + tid]       = f2b(y0);
  Yb[(size_t)row * DMODEL + tid + 256] = f2b(y1);
}

// ---------------------------------------------------------------------------
__global__ __launch_bounds__(256) void tok_embed_kernel(
    const int* __restrict__ toks, const float* __restrict__ emb,
    const float* __restrict__ pos, float* __restrict__ x, bf16u* __restrict__ xb)
{
  int sp = blockIdx.x, b = blockIdx.y;
  int s = sp + NCOND;
  int tok = toks[b * S_TOK + sp];
  const float* er = emb + (size_t)tok * DMODEL;
  const float* pr = pos + (size_t)s * DMODEL;
  size_t ro = ((size_t)b * SEQ + s) * DMODEL;
  for (int d = threadIdx.x; d < DMODEL; d += 256) {
    float v = er[d] * 22.62741699796952f + pr[d];   // sqrt(512)
    x[ro + d] = v; xb[ro + d] = f2b(v);
  }
}

// ---------------------------------------------------------------------------
__global__ __launch_bounds__(256) void cond_embed_kernel(
    const float* __restrict__ conds, const float* __restrict__ W1,
    const float* __restrict__ b1, const float* __restrict__ W2w,
    const float* __restrict__ b2, const float* __restrict__ nullc,
    const float* __restrict__ pos, float* __restrict__ x, bf16u* __restrict__ xb)
{
  int ci = blockIdx.x, b = blockIdx.y, tid = threadIdx.x;
  float c = conds[b * NCOND + ci];
  bool cn = isnan(c);
  float cm = cn ? 0.f : c;
  __shared__ float h1[DMODEL / 2];
  h1[tid] = fmaxf(cm * W1[ci * (DMODEL/2) + tid] + b1[ci * (DMODEL/2) + tid], 0.f);
  __syncthreads();
  for (int d = tid; d < DMODEL; d += 256) {
    float acc = b2[ci * DMODEL + d];
    for (int i = 0; i < DMODEL / 2; i++)
      acc = fmaf(h1[i], W2w[((size_t)ci * (DMODEL/2) + i) * DMODEL + d], acc);
    float ce = cn ? nullc[ci * DMODEL + d] : acc;
    float v = ce + pos[(size_t)ci * DMODEL + d];
    size_t ro = ((size_t)b * SEQ + ci) * DMODEL;
    x[ro + d] = v; xb[ro + d] = f2b(v);
  }
}

// ---------------------------------------------------------------------------
// E (fp32, one layer) -> bf16 scratch.
// ---------------------------------------------------------------------------
__global__ __launch_bounds__(256) void e_conv_kernel(
    const float* __restrict__ E, bf16u* __restrict__ Eb)
{
  int i = (blockIdx.x * 256 + threadIdx.x) * 4;
  float4 v = *(const float4*)&E[i];
  ushort4 o;
  o.x = f2b(v.x); o.y = f2b(v.y); o.z = f2b(v.z); o.w = f2b(v.w);
  *(ushort4*)&Eb[i] = o;
}

// ---------------------------------------------------------------------------
// MFMA flash attention (all-bf16 inputs). Block = 64 Q-rows of one (b,h).
// O (bf16) aliases Q buffer (block-private rows).
// ---------------------------------------------------------------------------
__global__ __launch_bounds__(256) void attn_kernel(
    const bf16u* Q, const bf16u* __restrict__ K, const bf16u* __restrict__ V,
    const bf16u* __restrict__ Eb16, const int* __restrict__ toks, bf16u* O)
{
  __shared__ bf16u Kb[64][72];
  __shared__ bf16u Vt[64][72];
  __shared__ bf16u Ebs[128][72];
  __shared__ bf16u Ps[64][72];
  __shared__ bf16u QEs[64][136];
  __shared__ float padv[64];

  const int tid  = threadIdx.x;
  const int lane = tid & 63;
  const int wave = tid >> 6;
  const int quad = lane >> 4;
  const int l16  = lane & 15;

  int bid = blockIdx.x;
  int g = bid >> 5;
  int w = bid & 31;
  int it = (w & 1) ? (31 - (w >> 1)) : (w >> 1);
  int b = g >> 3, h = g & 7;
  const int i0 = it * 64;

  // Q A-frags direct from global bf16 (16B aligned)
  const bf16u* qr = Q + ((size_t)(b * SEQ + i0 + wave * 16 + l16)) * DMODEL + h * DHEAD;
  s8frag q0 = *(const s8frag*)&qr[quad * 8];
  s8frag q1 = *(const s8frag*)&qr[32 + quad * 8];

  float m_run[4], l_run[4];
  f4frag acc[4];
#pragma unroll
  for (int r = 0; r < 4; r++) { m_run[r] = -1e30f; l_run[r] = 0.f; }
#pragma unroll
  for (int dt = 0; dt < 4; dt++) acc[dt] = (f4frag){0.f, 0.f, 0.f, 0.f};

  const int nst = it + 1;
  for (int js = 0; js < nst; js++) {
    const int j0 = js * 64;
    __syncthreads();

    // K tile: 4096 bf16, 16B chunks
#pragma unroll
    for (int e = 0; e < 2; e++) {
      int c = e * 256 + tid;
      int jr = c >> 3, doff = (c & 7) * 8;
      *(uint4*)&Kb[jr][doff] =
          *(const uint4*)&K[((size_t)(b * SEQ + j0 + jr)) * DMODEL + h * DHEAD + doff];
    }
    // V transposed: Vt[d][j]
#pragma unroll
    for (int e = 0; e < 8; e++) {
      int idx = e * 256 + tid;
      int d = idx & 63, jp = idx >> 6;   // jp 0..31
      size_t g0 = ((size_t)(b * SEQ + j0 + 2 * jp)) * DMODEL + h * DHEAD + d;
      unsigned int pv = (unsigned int)V[g0] | ((unsigned int)V[g0 + DMODEL] << 16);
      *(unsigned int*)&Vt[d][2 * jp] = pv;
    }
    // E band rows m0..m0+127 (clamped)
    const int m0 = SEQ - 64 - i0 + j0;
#pragma unroll
    for (int e = 0; e < 4; e++) {
      int c = e * 256 + tid;
      int er = c >> 3, doff = (c & 7) * 8;
      int row = m0 + er; if (row > SEQ - 1) row = SEQ - 1;
      *(uint4*)&Ebs[er][doff] = *(const uint4*)&Eb16[(size_t)row * DHEAD + doff];
    }
    if (tid < 64) {
      int j = j0 + tid;
      bool pad = (j >= NCOND) && (toks[b * S_TOK + j - NCOND] == 0);
      padv[tid] = pad ? -1e30f : 0.f;
    }
    __syncthreads();

    // QK^T
    f4frag sc[4];
#pragma unroll
    for (int nt = 0; nt < 4; nt++) {
      s8frag k0 = *(const s8frag*)&Kb[nt * 16 + l16][quad * 8];
      s8frag k1 = *(const s8frag*)&Kb[nt * 16 + l16][32 + quad * 8];
      f4frag c = (f4frag){0.f, 0.f, 0.f, 0.f};
      c = __builtin_amdgcn_mfma_f32_16x16x32_bf16(q0, k0, c, 0, 0, 0);
      c = __builtin_amdgcn_mfma_f32_16x16x32_bf16(q1, k1, c, 0, 0, 0);
      sc[nt] = c;
    }

    // Q.E band -> QEs
#pragma unroll
    for (int ct = 0; ct < 8; ct++) {
      s8frag e0 = *(const s8frag*)&Ebs[ct * 16 + l16][quad * 8];
      s8frag e1 = *(const s8frag*)&Ebs[ct * 16 + l16][32 + quad * 8];
      f4frag c = (f4frag){0.f, 0.f, 0.f, 0.f};
      c = __builtin_amdgcn_mfma_f32_16x16x32_bf16(q0, e0, c, 0, 0, 0);
      c = __builtin_amdgcn_mfma_f32_16x16x32_bf16(q1, e1, c, 0, 0, 0);
#pragma unroll
      for (int r = 0; r < 4; r++)
        QEs[wave * 16 + quad * 4 + r][ct * 16 + l16] = f2b(c[r]);
    }

    // scores + online softmax
    float s[4][4], mx[4];
#pragma unroll
    for (int r = 0; r < 4; r++) {
      int rloc = wave * 16 + quad * 4 + r;
      int ig = i0 + rloc;
#pragma unroll
      for (int nt = 0; nt < 4; nt++) {
        int jl = nt * 16 + l16;
        float qe = b2f(QEs[rloc][63 + jl - rloc]);
        float sv = (sc[nt][r] + qe) * 0.125f + padv[jl];
        if (j0 + jl > ig) sv = -1e30f;
        s[nt][r] = sv;
      }
      float m = fmaxf(fmaxf(s[0][r], s[1][r]), fmaxf(s[2][r], s[3][r]));
      m = fmaxf(m, __shfl_xor(m, 1));
      m = fmaxf(m, __shfl_xor(m, 2));
      m = fmaxf(m, __shfl_xor(m, 4));
      m = fmaxf(m, __shfl_xor(m, 8));
      mx[r] = m;
    }
    float alpha[4];
#pragma unroll
    for (int r = 0; r < 4; r++) {
      float m_new = fmaxf(m_run[r], mx[r]);
      alpha[r] = __expf(m_run[r] - m_new);
      float psum = 0.f;
      int rloc = wave * 16 + quad * 4 + r;
#pragma unroll
      for (int nt = 0; nt < 4; nt++) {
        float p = __expf(s[nt][r] - m_new);
        Ps[rloc][nt * 16 + l16] = f2b(p);
        psum += p;
      }
      psum += __shfl_xor(psum, 1);
      psum += __shfl_xor(psum, 2);
      psum += __shfl_xor(psum, 4);
      psum += __shfl_xor(psum, 8);
      l_run[r] = l_run[r] * alpha[r] + psum;
      m_run[r] = m_new;
    }
#pragma unroll
    for (int dt = 0; dt < 4; dt++)
#pragma unroll
      for (int r = 0; r < 4; r++) acc[dt][r] *= alpha[r];

    // P @ V
    s8frag p0 = *(const s8frag*)&Ps[wave * 16 + l16][quad * 8];
    s8frag p1 = *(const s8frag*)&Ps[wave * 16 + l16][32 + quad * 8];
#pragma unroll
    for (int dt = 0; dt < 4; dt++) {
      s8frag v0 = *(const s8frag*)&Vt[dt * 16 + l16][quad * 8];
      s8frag v1 = *(const s8frag*)&Vt[dt * 16 + l16][32 + quad * 8];
      acc[dt] = __builtin_amdgcn_mfma_f32_16x16x32_bf16(p0, v0, acc[dt], 0, 0, 0);
      acc[dt] = __builtin_amdgcn_mfma_f32_16x16x32_bf16(p1, v1, acc[dt], 0, 0, 0);
    }
  }

  // normalize + write bf16 (O aliases Q; block-private rows)
#pragma unroll
  for (int r = 0; r < 4; r++) {
    float inv = 1.0f / l_run[r];
    int ig = i0 + wave * 16 + quad * 4 + r;
    bf16u* ob = O + ((size_t)(b * SEQ + ig)) * DMODEL + h * DHEAD;
#pragma unroll
    for (int dt = 0; dt < 4; dt++)
      ob[dt * 16 + l16] = f2b(acc[dt][r] * inv);
  }
}

// ---------------------------------------------------------------------------
extern "C" void kernel_launch(void* const* d_in, const int* in_sizes, int n_in,
                              void* d_out, int out_size, void* d_ws, size_t ws_size,
                              hipStream_t stream) {
  const int*   toks  = (const int*)  d_in[0];
  const float* conds = (const float*)d_in[1];
  const float* ttc   = (const float*)d_in[2];
  const float* emb   = (const float*)d_in[3];
  const float* pos   = (const float*)d_in[4];
  const float* cW1   = (const float*)d_in[5];
  const float* cb1   = (const float*)d_in[6];
  const float* cW2   = (const float*)d_in[7];
  const float* cb2   = (const float*)d_in[8];
  const float* nullc = (const float*)d_in[9];
  const float* ttcW  = (const float*)d_in[10];
  const float* ttcb  = (const float*)d_in[11];
  const float* Wq    = (const float*)d_in[12];
  const float* Wk    = (const float*)d_in[13];
  const float* Wv    = (const float*)d_in[14];
  const float* Wo    = (const float*)d_in[15];
  const float* bq    = (const float*)d_in[16];
  const float* bk    = (const float*)d_in[17];
  const float* bv    = (const float*)d_in[18];
  const float* bo    = (const float*)d_in[19];
  const float* E     = (const float*)d_in[20];
  const float* fW1   = (const float*)d_in[21];
  const float* fb1   = (const float*)d_in[22];
  const float* fW2   = (const float*)d_in[23];
  const float* fb2   = (const float*)d_in[24];
  const float* ln1g  = (const float*)d_in[25];
  const float* ln1b  = (const float*)d_in[26];
  const float* ln2g  = (const float*)d_in[27];
  const float* ln2b  = (const float*)d_in[28];
  const float* fcW   = (const float*)d_in[29];
  const float* fcb   = (const float*)d_in[30];

  const size_t MB1 = 1024 * 1024;
  char* p = (char*)d_ws;
  float* x    = (float*)p; p += 8 * MB1;
  float* out1 = (float*)p; p += 8 * MB1;
  float* t1   = (float*)p; p += 8 * MB1;
  bf16u* xb   = (bf16u*)p; p += 4 * MB1;   // also serves as out1b (lifetimes disjoint)
  bf16u* qb   = (bf16u*)p; p += 4 * MB1;   // q, then attention output
  bf16u* kb   = (bf16u*)p; p += 4 * MB1;
  bf16u* vb   = (bf16u*)p; p += 4 * MB1;
  bf16u* hidb = (bf16u*)p; p += 16 * MB1;
  bf16u* ebf  = (bf16u*)p; p += 256 * 1024;
  bf16u* WqT  = (bf16u*)p; p += 512 * 1024;
  bf16u* WkT  = (bf16u*)p; p += 512 * 1024;
  bf16u* WvT  = (bf16u*)p; p += 512 * 1024;
  bf16u* WoT  = (bf16u*)p; p += 512 * 1024;
  bf16u* W1T  = (bf16u*)p; p += 2 * MB1;
  bf16u* W2T  = (bf16u*)p; p += 2 * MB1;
  bf16u* fcT  = (bf16u*)p; p += 512 * 1024;   // ~63 MB total

  cond_embed_kernel<<<dim3(NCOND, BATCH), 256, 0, stream>>>(
      conds, cW1, cb1, cW2, cb2, nullc, pos, x, xb);
  tok_embed_kernel<<<dim3(S_TOK, BATCH), 256, 0, stream>>>(toks, emb, pos, x, xb);

  dim3 gQKV(MROWS / 128, DMODEL / 128);    // (32,4)
  dim3 gFF1(MROWS / 128, DINNER / 128);    // (32,16)

  for (int l = 0; l < NLAYER; l++) {
    wt_kernel<<<768, 256, 0, stream>>>(Wq, Wk, Wv, Wo, fW1, fW2,
        WqT, WkT, WvT, WoT, W1T, W2T, l);

    mgemm<<<gQKV, 256, 0, stream>>>(xb, WqT, bq + l * DMODEL, nullptr,
        nullptr, qb, MROWS, DMODEL, DMODEL, 0, nullptr, nullptr, nullptr);
    mgemm<<<gQKV, 256, 0, stream>>>(xb, WkT, bk + l * DMODEL, nullptr,
        nullptr, kb, MROWS, DMODEL, DMODEL, 0, nullptr, nullptr, nullptr);
    mgemm<<<gQKV, 256, 0, stream>>>(xb, WvT, bv + l * DMODEL, nullptr,
        nullptr, vb, MROWS, DMODEL, DMODEL, 0, nullptr, nullptr, nullptr);

    e_conv_kernel<<<(SEQ * DHEAD) / 1024, 256, 0, stream>>>(
        E + (size_t)l * SEQ * DHEAD, ebf);
    attn_kernel<<<BATCH * NHEAD * (SEQ / 64), 256, 0, stream>>>(
        qb, kb, vb, ebf, toks, qb);

    // t1 = attn @ Wo + bo + x
    mgemm<<<gQKV, 256, 0, stream>>>(qb, WoT, bo + l * DMODEL, x,
        t1, nullptr, MROWS, DMODEL, DMODEL, 1, nullptr, nullptr, nullptr);
    ln_kernel<<<MROWS, 256, 0, stream>>>(t1, ln1g + l * DMODEL, ln1b + l * DMODEL,
        out1, xb);

    // hid = relu(out1 @ W1 + b1) + chord  (bf16)
    mgemm<<<gFF1, 256, 0, stream>>>(xb, W1T, fb1 + l * DINNER, nullptr,
        nullptr, hidb, MROWS, DINNER, DMODEL, 2, ttc, ttcW, ttcb);
    // t1 = hid @ W2 + b2 + out1
    mgemm<<<gQKV, 256, 0, stream>>>(hidb, W2T, fb2 + l * DMODEL, out1,
        t1, nullptr, MROWS, DMODEL, DINNER, 1, nullptr, nullptr, nullptr);
    ln_kernel<<<MROWS, 256, 0, stream>>>(t1, ln2g + l * DMODEL, ln2b + l * DMODEL,
        x, xb);
  }

  // logits = x @ fc_W + fc_b  (fp32 out)
  wt_kernel<<<64, 256, 0, stream>>>(fcW, fcW, fcW, fcW, fcW, fcW,
      fcT, fcT, fcT, fcT, fcT, fcT, 0);
  mgemm<<<gQKV, 256, 0, stream>>>(xb, fcT, fcb, nullptr,
      (float*)d_out, nullptr, MROWS, VOCAB, DMODEL, 3, nullptr, nullptr, nullptr);
}

// Round 6
// 1836.524 us; speedup vs baseline: 10.3177x; 1.1451x over previous
//
#include <hip/hip_runtime.h>
#include <hip/hip_bf16.h>
#include <math.h>

// ---- problem constants ----
#define BATCH  2
#define S_TOK  2046
#define NCOND  2
#define SEQ    2048
#define DMODEL 512
#define DINNER 2048
#define NHEAD  8
#define DHEAD  64
#define NLAYER 6
#define VOCAB  512
#define MROWS  (BATCH*SEQ)   // 4096 rows

typedef unsigned short bf16u;
typedef __attribute__((ext_vector_type(8))) short s8frag;   // 8 bf16 (4 VGPRs)
typedef __attribute__((ext_vector_type(4))) float f4frag;   // 4 fp32 acc

__device__ __forceinline__ float b2f(bf16u u) {
  union { unsigned int i; float f; } v; v.i = ((unsigned int)u) << 16; return v.f;
}
__device__ __forceinline__ bf16u f2b(float f) {
  union { float f; unsigned int i; } v; v.f = f;
  unsigned int x = v.i;
  return (bf16u)((x + 0x7fffu + ((x >> 16) & 1u)) >> 16);
}

// ---------------------------------------------------------------------------
// Weight transpose + bf16 convert: dst[N][K] (bf16) = src[K][N] (fp32).
// ---------------------------------------------------------------------------
__global__ __launch_bounds__(256) void wt_kernel(
    const float* __restrict__ Wq, const float* __restrict__ Wk,
    const float* __restrict__ Wv, const float* __restrict__ Wo,
    const float* __restrict__ W1, const float* __restrict__ W2,
    bf16u* __restrict__ qT, bf16u* __restrict__ kT,
    bf16u* __restrict__ vT, bf16u* __restrict__ oT,
    bf16u* __restrict__ w1T, bf16u* __restrict__ w2T, int layer)
{
  int bid = blockIdx.x;
  const float* src; bf16u* dst; int K, N, kt, nt;
  if (bid < 256) {
    int mat = bid >> 6, t = bid & 63;
    const float* s4[4] = {Wq, Wk, Wv, Wo};
    bf16u*       d4[4] = {qT, kT, vT, oT};
    src = s4[mat] + (size_t)layer * DMODEL * DMODEL; dst = d4[mat];
    K = DMODEL; N = DMODEL; kt = t >> 3; nt = t & 7;
  } else if (bid < 512) {
    int t = bid - 256;
    src = W1 + (size_t)layer * DMODEL * DINNER; dst = w1T;
    K = DMODEL; N = DINNER; kt = t >> 5; nt = t & 31;
  } else {
    int t = bid - 512;
    src = W2 + (size_t)layer * DINNER * DMODEL; dst = w2T;
    K = DINNER; N = DMODEL; kt = t >> 3; nt = t & 7;
  }
  __shared__ bf16u Ls[64][66];
  int tid = threadIdx.x;
  int c = tid & 63, r4 = tid >> 6;
#pragma unroll
  for (int i = 0; i < 16; i++) {
    int r = i * 4 + r4;
    Ls[r][c] = f2b(src[(size_t)(kt * 64 + r) * N + nt * 64 + c]);
  }
  __syncthreads();
#pragma unroll
  for (int i = 0; i < 16; i++) {
    int rr = i * 4 + r4;
    dst[(size_t)(nt * 64 + rr) * K + kt * 64 + c] = Ls[c][rr];
  }
}

// ---------------------------------------------------------------------------
// MFMA GEMM, template RB = m-tiles per wave (4 -> 128x128 tile, 2 -> 64x128).
// modes: 0 +bias->bf16 ; 1 +bias+R->fp32 ; 2 relu(+bias)+chord->bf16 ;
//        3 +bias->fp32 ; 4 fused-QKV routing (bias b0/b1/b2 per 512-col range)
// ---------------------------------------------------------------------------
template <int RB>
__global__ __launch_bounds__(256) void mgemm(
    const bf16u* __restrict__ A, const bf16u* __restrict__ Wt,
    const float* __restrict__ b0, const float* __restrict__ b1,
    const float* __restrict__ b2, const float* __restrict__ R,
    float* __restrict__ Cf, bf16u* __restrict__ Cb,
    int M, int N, int K, int mode,
    const float* __restrict__ ttc, const float* __restrict__ ttcW,
    const float* __restrict__ ttcb)
{
  __shared__ bf16u Ab[RB * 32][40];
  __shared__ bf16u Bb[128][40];
  const int tid = threadIdx.x;
  const int lane = tid & 63, wave = tid >> 6;
  const int quad = lane >> 4, l16 = lane & 15;
  const int wm = wave >> 1, wn = wave & 1;
  const int row0 = blockIdx.x * (RB * 32), col0 = blockIdx.y * 128;

  f4frag acc[RB][4];
#pragma unroll
  for (int i = 0; i < RB; i++)
#pragma unroll
    for (int j = 0; j < 4; j++) acc[i][j] = (f4frag){0.f, 0.f, 0.f, 0.f};

  for (int k0 = 0; k0 < K; k0 += 32) {
    if (k0) __syncthreads();
#pragma unroll
    for (int i = 0; i < RB / 2; i++) {
      int c = tid + i * 256;
      int r = c >> 2, koff = (c & 3) * 8;
      *(uint4*)&Ab[r][koff] = *(const uint4*)&A[(size_t)(row0 + r) * K + k0 + koff];
    }
#pragma unroll
    for (int i = 0; i < 2; i++) {
      int c = tid + i * 256;
      int r = c >> 2, koff = (c & 3) * 8;
      *(uint4*)&Bb[r][koff] = *(const uint4*)&Wt[(size_t)(col0 + r) * K + k0 + koff];
    }
    __syncthreads();
    s8frag af[RB], bfr[4];
#pragma unroll
    for (int t = 0; t < RB; t++)
      af[t] = *(const s8frag*)&Ab[wm * (RB * 16) + t * 16 + l16][quad * 8];
#pragma unroll
    for (int t = 0; t < 4; t++)
      bfr[t] = *(const s8frag*)&Bb[wn * 64 + t * 16 + l16][quad * 8];
#pragma unroll
    for (int mt = 0; mt < RB; mt++)
#pragma unroll
      for (int nt = 0; nt < 4; nt++)
        acc[mt][nt] = __builtin_amdgcn_mfma_f32_16x16x32_bf16(
            af[mt], bfr[nt], acc[mt][nt], 0, 0, 0);
  }

#pragma unroll
  for (int mt = 0; mt < RB; mt++) {
#pragma unroll
    for (int r = 0; r < 4; r++) {
      int m = row0 + wm * (RB * 16) + mt * 16 + quad * 4 + r;
      float tval = 0.f;
      if (mode == 2) {
        int bb = m >> 11, s = m & (SEQ - 1);
        int sp = (s < NCOND) ? 0 : (s - NCOND);
        tval = 8.0f - ttc[bb * S_TOK + sp];
      }
#pragma unroll
      for (int nt = 0; nt < 4; nt++) {
        int n = col0 + wn * 64 + nt * 16 + l16;
        if (mode == 4) {
          int sel = n >> 9, nn = n & 511;
          float bv = (sel == 0) ? b0[nn] : ((sel == 1) ? b1[nn] : b2[nn]);
          float v = acc[mt][nt][r] + bv;
          Cb[(size_t)sel * MROWS * DMODEL + (size_t)m * DMODEL + nn] = f2b(v);
        } else {
          float v = acc[mt][nt][r] + b0[n];
          if (mode == 1)      v += R[(size_t)m * N + n];
          else if (mode == 2) v = fmaxf(v, 0.f) + tval * ttcW[n] + ttcb[n];
          if (mode == 0 || mode == 2) Cb[(size_t)m * N + n] = f2b(v);
          else                        Cf[(size_t)m * N + n] = v;
        }
      }
    }
  }
}

// ---------------------------------------------------------------------------
// LayerNorm over D=512; fp32 Y (residual) + bf16 Yb (next GEMM A).
// ---------------------------------------------------------------------------
__global__ __launch_bounds__(256) void ln_kernel(
    const float* __restrict__ X, const float* __restrict__ g,
    const float* __restrict__ bta, float* __restrict__ Y, bf16u* __restrict__ Yb)
{
  int row = blockIdx.x, tid = threadIdx.x;
  const float* xr = X + (size_t)row * DMODEL;
  float x0 = xr[tid], x1 = xr[tid + 256];
  __shared__ float red[8];
  int wv = tid >> 6, ln = tid & 63;
  float s = x0 + x1;
  for (int off = 32; off; off >>= 1) s += __shfl_xor(s, off);
  if (ln == 0) red[wv] = s;
  __syncthreads();
  float mu = (red[0] + red[1] + red[2] + red[3]) * (1.0f / DMODEL);
  float d0 = x0 - mu, d1 = x1 - mu;
  float vs = d0 * d0 + d1 * d1;
  for (int off = 32; off; off >>= 1) vs += __shfl_xor(vs, off);
  if (ln == 0) red[4 + wv] = vs;
  __syncthreads();
  float var = (red[4] + red[5] + red[6] + red[7]) * (1.0f / DMODEL);
  float rstd = rsqrtf(var + 1e-6f);
  float y0 = d0 * rstd * g[tid]       + bta[tid];
  float y1 = d1 * rstd * g[tid + 256] + bta[tid + 256];
  Y [(size_t)row * DMODEL + tid]       = y0;
  Y [(size_t)row * DMODEL + tid + 256] = y1;
  Yb[(size_t)row * DMODEL + tid]       = f2b(y0);
  Yb[(size_t)row * DMODEL + tid + 256] = f2b(y1);
}

// ---------------------------------------------------------------------------
__global__ __launch_bounds__(256) void tok_embed_kernel(
    const int* __restrict__ toks, const float* __restrict__ emb,
    const float* __restrict__ pos, float* __restrict__ x, bf16u* __restrict__ xb)
{
  int sp = blockIdx.x, b = blockIdx.y;
  int s = sp + NCOND;
  int tok = toks[b * S_TOK + sp];
  const float* er = emb + (size_t)tok * DMODEL;
  const float* pr = pos + (size_t)s * DMODEL;
  size_t ro = ((size_t)b * SEQ + s) * DMODEL;
  for (int d = threadIdx.x; d < DMODEL; d += 256) {
    float v = er[d] * 22.62741699796952f + pr[d];   // sqrt(512)
    x[ro + d] = v; xb[ro + d] = f2b(v);
  }
}

// ---------------------------------------------------------------------------
__global__ __launch_bounds__(256) void cond_embed_kernel(
    const float* __restrict__ conds, const float* __restrict__ W1,
    const float* __restrict__ b1, const float* __restrict__ W2w,
    const float* __restrict__ b2, const float* __restrict__ nullc,
    const float* __restrict__ pos, float* __restrict__ x, bf16u* __restrict__ xb)
{
  int ci = blockIdx.x, b = blockIdx.y, tid = threadIdx.x;
  float c = conds[b * NCOND + ci];
  bool cn = isnan(c);
  float cm = cn ? 0.f : c;
  __shared__ float h1[DMODEL / 2];
  h1[tid] = fmaxf(cm * W1[ci * (DMODEL/2) + tid] + b1[ci * (DMODEL/2) + tid], 0.f);
  __syncthreads();
  for (int d = tid; d < DMODEL; d += 256) {
    float acc = b2[ci * DMODEL + d];
    for (int i = 0; i < DMODEL / 2; i++)
      acc = fmaf(h1[i], W2w[((size_t)ci * (DMODEL/2) + i) * DMODEL + d], acc);
    float ce = cn ? nullc[ci * DMODEL + d] : acc;
    float v = ce + pos[(size_t)ci * DMODEL + d];
    size_t ro = ((size_t)b * SEQ + ci) * DMODEL;
    x[ro + d] = v; xb[ro + d] = f2b(v);
  }
}

// ---------------------------------------------------------------------------
__global__ __launch_bounds__(256) void e_conv_kernel(
    const float* __restrict__ E, bf16u* __restrict__ Eb)
{
  int i = (blockIdx.x * 256 + threadIdx.x) * 4;
  float4 v = *(const float4*)&E[i];
  ushort4 o;
  o.x = f2b(v.x); o.y = f2b(v.y); o.z = f2b(v.z); o.w = f2b(v.w);
  *(ushort4*)&Eb[i] = o;
}

// ---------------------------------------------------------------------------
// Split-K MFMA flash attention, phase 1. Block = (b,h, 64-row q-tile it,
// key-chunk c of <=8 64-key steps). Writes partial m,l,acc (bf16).
// Vt uses XOR swizzle (col-block ^ row>>3) -> conflict-free transpose.
// ---------------------------------------------------------------------------
__global__ __launch_bounds__(256) void attn_part(
    const bf16u* __restrict__ Q, const bf16u* __restrict__ K,
    const bf16u* __restrict__ V, const bf16u* __restrict__ Eb16,
    const int* __restrict__ toks, bf16u* __restrict__ pacc,
    float* __restrict__ pstat)
{
  const int bid = blockIdx.x;
  const int g  = bid >> 7;          // (b,h)
  const int it = (bid >> 2) & 31;   // q-tile
  const int c  = bid & 3;           // key chunk
  if (8 * c > it) return;
  const int b = g >> 3, h = g & 7;
  const int i0 = it * 64;

  __shared__ bf16u Kb[64][72];
  __shared__ bf16u Vt[64][72];
  __shared__ bf16u Ebs[128][72];
  __shared__ bf16u Ps[64][72];
  __shared__ bf16u QEs[64][136];
  __shared__ float padv[64];

  const int tid  = threadIdx.x;
  const int lane = tid & 63;
  const int wave = tid >> 6;
  const int quad = lane >> 4;
  const int l16  = lane & 15;

  const bf16u* qr = Q + ((size_t)(b * SEQ + i0 + wave * 16 + l16)) * DMODEL + h * DHEAD;
  s8frag q0 = *(const s8frag*)&qr[quad * 8];
  s8frag q1 = *(const s8frag*)&qr[32 + quad * 8];

  float m_run[4], l_run[4];
  f4frag acc[4];
#pragma unroll
  for (int r = 0; r < 4; r++) { m_run[r] = -1e30f; l_run[r] = 0.f; }
#pragma unroll
  for (int dt = 0; dt < 4; dt++) acc[dt] = (f4frag){0.f, 0.f, 0.f, 0.f};

  const int js0 = 8 * c;
  const int jsE = min(8 * c + 8, it + 1);
  for (int js = js0; js < jsE; js++) {
    const int j0 = js * 64;
    __syncthreads();

    // K tile
#pragma unroll
    for (int e = 0; e < 2; e++) {
      int cc = e * 256 + tid;
      int jr = cc >> 3, doff = (cc & 7) * 8;
      *(uint4*)&Kb[jr][doff] =
          *(const uint4*)&K[((size_t)(b * SEQ + j0 + jr)) * DMODEL + h * DHEAD + doff];
    }
    // V transposed with XOR swizzle: logical Vt[d][j], col-block ^= d>>3
#pragma unroll
    for (int e = 0; e < 8; e++) {
      int idx = e * 256 + tid;
      int d = idx & 63, jp = idx >> 6;   // jp 0..31
      size_t g0 = ((size_t)(b * SEQ + j0 + 2 * jp)) * DMODEL + h * DHEAD + d;
      unsigned int pv = (unsigned int)V[g0] | ((unsigned int)V[g0 + DMODEL] << 16);
      int colb = (jp >> 2) ^ (d >> 3);
      *(unsigned int*)&Vt[d][colb * 8 + 2 * (jp & 3)] = pv;
    }
    // E band
    const int m0 = SEQ - 64 - i0 + j0;
#pragma unroll
    for (int e = 0; e < 4; e++) {
      int cc = e * 256 + tid;
      int er = cc >> 3, doff = (cc & 7) * 8;
      int row = m0 + er; if (row > SEQ - 1) row = SEQ - 1;
      *(uint4*)&Ebs[er][doff] = *(const uint4*)&Eb16[(size_t)row * DHEAD + doff];
    }
    if (tid < 64) {
      int j = j0 + tid;
      bool pad = (j >= NCOND) && (toks[b * S_TOK + j - NCOND] == 0);
      padv[tid] = pad ? -1e30f : 0.f;
    }
    __syncthreads();

    // QK^T
    f4frag sc[4];
#pragma unroll
    for (int nt = 0; nt < 4; nt++) {
      s8frag k0 = *(const s8frag*)&Kb[nt * 16 + l16][quad * 8];
      s8frag k1 = *(const s8frag*)&Kb[nt * 16 + l16][32 + quad * 8];
      f4frag cc = (f4frag){0.f, 0.f, 0.f, 0.f};
      cc = __builtin_amdgcn_mfma_f32_16x16x32_bf16(q0, k0, cc, 0, 0, 0);
      cc = __builtin_amdgcn_mfma_f32_16x16x32_bf16(q1, k1, cc, 0, 0, 0);
      sc[nt] = cc;
    }

    // Q.E band -> QEs
#pragma unroll
    for (int ct = 0; ct < 8; ct++) {
      s8frag e0 = *(const s8frag*)&Ebs[ct * 16 + l16][quad * 8];
      s8frag e1 = *(const s8frag*)&Ebs[ct * 16 + l16][32 + quad * 8];
      f4frag cc = (f4frag){0.f, 0.f, 0.f, 0.f};
      cc = __builtin_amdgcn_mfma_f32_16x16x32_bf16(q0, e0, cc, 0, 0, 0);
      cc = __builtin_amdgcn_mfma_f32_16x16x32_bf16(q1, e1, cc, 0, 0, 0);
#pragma unroll
      for (int r = 0; r < 4; r++)
        QEs[wave * 16 + quad * 4 + r][ct * 16 + l16] = f2b(cc[r]);
    }

    // scores + online softmax
    float s[4][4], mx[4];
#pragma unroll
    for (int r = 0; r < 4; r++) {
      int rloc = wave * 16 + quad * 4 + r;
      int ig = i0 + rloc;
#pragma unroll
      for (int nt = 0; nt < 4; nt++) {
        int jl = nt * 16 + l16;
        float qe = b2f(QEs[rloc][63 + jl - rloc]);
        float sv = (sc[nt][r] + qe) * 0.125f + padv[jl];
        if (j0 + jl > ig) sv = -1e30f;
        s[nt][r] = sv;
      }
      float m = fmaxf(fmaxf(s[0][r], s[1][r]), fmaxf(s[2][r], s[3][r]));
      m = fmaxf(m, __shfl_xor(m, 1));
      m = fmaxf(m, __shfl_xor(m, 2));
      m = fmaxf(m, __shfl_xor(m, 4));
      m = fmaxf(m, __shfl_xor(m, 8));
      mx[r] = m;
    }
    float alpha[4];
#pragma unroll
    for (int r = 0; r < 4; r++) {
      float m_new = fmaxf(m_run[r], mx[r]);
      alpha[r] = __expf(m_run[r] - m_new);
      float psum = 0.f;
      int rloc = wave * 16 + quad * 4 + r;
#pragma unroll
      for (int nt = 0; nt < 4; nt++) {
        float p = __expf(s[nt][r] - m_new);
        Ps[rloc][nt * 16 + l16] = f2b(p);
        psum += p;
      }
      psum += __shfl_xor(psum, 1);
      psum += __shfl_xor(psum, 2);
      psum += __shfl_xor(psum, 4);
      psum += __shfl_xor(psum, 8);
      l_run[r] = l_run[r] * alpha[r] + psum;
      m_run[r] = m_new;
    }
#pragma unroll
    for (int dt = 0; dt < 4; dt++)
#pragma unroll
      for (int r = 0; r < 4; r++) acc[dt][r] *= alpha[r];

    // P @ V (Vt swizzled reads)
    s8frag p0 = *(const s8frag*)&Ps[wave * 16 + l16][quad * 8];
    s8frag p1 = *(const s8frag*)&Ps[wave * 16 + l16][32 + quad * 8];
#pragma unroll
    for (int dt = 0; dt < 4; dt++) {
      int row = dt * 16 + l16;
      s8frag v0 = *(const s8frag*)&Vt[row][(quad       ^ (row >> 3)) * 8];
      s8frag v1 = *(const s8frag*)&Vt[row][((quad + 4) ^ (row >> 3)) * 8];
      acc[dt] = __builtin_amdgcn_mfma_f32_16x16x32_bf16(p0, v0, acc[dt], 0, 0, 0);
      acc[dt] = __builtin_amdgcn_mfma_f32_16x16x32_bf16(p1, v1, acc[dt], 0, 0, 0);
    }
  }

  // ---- write partials ----
#pragma unroll
  for (int r = 0; r < 4; r++) {
    int rloc = wave * 16 + quad * 4 + r;
    if (l16 == 0) {
      pstat[(size_t)bid * 128 + rloc]      = m_run[r];
      pstat[(size_t)bid * 128 + 64 + rloc] = l_run[r];
    }
#pragma unroll
    for (int dt = 0; dt < 4; dt++)
      pacc[(size_t)bid * 4096 + rloc * 64 + dt * 16 + l16] = f2b(acc[dt][r]);
  }
}

// ---------------------------------------------------------------------------
// Phase 2: merge <=4 chunk partials per (b,h,q-tile); write O (bf16) to qb.
// ---------------------------------------------------------------------------
__global__ __launch_bounds__(256) void attn_combine(
    const bf16u* __restrict__ pacc, const float* __restrict__ pstat,
    bf16u* __restrict__ O)
{
  int bid = blockIdx.x;             // 512 = g*32 + it
  int g = bid >> 5, it = bid & 31;
  int b = g >> 3, h = g & 7;
  int i0 = it * 64;
  int nc = (it >> 3) + 1;           // chunks
  int tid = threadIdx.x;
  int row = tid >> 2, ql = tid & 3; // 16 cols per thread

  float m_tot = -1e30f;
  float mc[4], lc[4];
#pragma unroll
  for (int c = 0; c < 4; c++) {
    if (c < nc) {
      size_t pb = (size_t)(bid * 4 + c) * 128;
      mc[c] = pstat[pb + row];
      lc[c] = pstat[pb + 64 + row];
      m_tot = fmaxf(m_tot, mc[c]);
    }
  }
  float l_tot = 0.f, w[4];
#pragma unroll
  for (int c = 0; c < 4; c++) {
    if (c < nc) { w[c] = __expf(mc[c] - m_tot); l_tot += w[c] * lc[c]; }
    else w[c] = 0.f;
  }
  float inv = 1.0f / l_tot;

  float out[16];
#pragma unroll
  for (int k = 0; k < 16; k++) out[k] = 0.f;
#pragma unroll
  for (int c = 0; c < 4; c++) {
    if (c >= nc) break;
    const bf16u* pa = pacc + (size_t)(bid * 4 + c) * 4096 + row * 64 + ql * 16;
#pragma unroll
    for (int k = 0; k < 16; k++) out[k] += w[c] * b2f(pa[k]);
  }
  bf16u* ob = O + ((size_t)(b * SEQ + i0 + row)) * DMODEL + h * DHEAD + ql * 16;
#pragma unroll
  for (int k = 0; k < 16; k++) ob[k] = f2b(out[k] * inv);
}

// ---------------------------------------------------------------------------
extern "C" void kernel_launch(void* const* d_in, const int* in_sizes, int n_in,
                              void* d_out, int out_size, void* d_ws, size_t ws_size,
                              hipStream_t stream) {
  const int*   toks  = (const int*)  d_in[0];
  const float* conds = (const float*)d_in[1];
  const float* ttc   = (const float*)d_in[2];
  const float* emb   = (const float*)d_in[3];
  const float* pos   = (const float*)d_in[4];
  const float* cW1   = (const float*)d_in[5];
  const float* cb1   = (const float*)d_in[6];
  const float* cW2   = (const float*)d_in[7];
  const float* cb2   = (const float*)d_in[8];
  const float* nullc = (const float*)d_in[9];
  const float* ttcW  = (const float*)d_in[10];
  const float* ttcb  = (const float*)d_in[11];
  const float* Wq    = (const float*)d_in[12];
  const float* Wk    = (const float*)d_in[13];
  const float* Wv    = (const float*)d_in[14];
  const float* Wo    = (const float*)d_in[15];
  const float* bq    = (const float*)d_in[16];
  const float* bk    = (const float*)d_in[17];
  const float* bv    = (const float*)d_in[18];
  const float* bo    = (const float*)d_in[19];
  const float* E     = (const float*)d_in[20];
  const float* fW1   = (const float*)d_in[21];
  const float* fb1   = (const float*)d_in[22];
  const float* fW2   = (const float*)d_in[23];
  const float* fb2   = (const float*)d_in[24];
  const float* ln1g  = (const float*)d_in[25];
  const float* ln1b  = (const float*)d_in[26];
  const float* ln2g  = (const float*)d_in[27];
  const float* ln2b  = (const float*)d_in[28];
  const float* fcW   = (const float*)d_in[29];
  const float* fcb   = (const float*)d_in[30];

  const size_t MB1 = 1024 * 1024;
  const size_t MD = (size_t)MROWS * DMODEL;
  char* p = (char*)d_ws;
  float* x    = (float*)p; p += 8 * MB1;
  float* out1 = (float*)p; p += 8 * MB1;
  float* t1   = (float*)p; p += 8 * MB1;
  bf16u* xb   = (bf16u*)p; p += 4 * MB1;
  bf16u* qkvb = (bf16u*)p; p += 12 * MB1;   // q | k | v contiguous
  bf16u* hidb = (bf16u*)p; p += 16 * MB1;   // FFN hidden; aliased as pacc
  float* pstat= (float*)p; p += 1 * MB1;    // 2048 x 128
  bf16u* ebf  = (bf16u*)p; p += 256 * 1024;
  bf16u* WqkvT= (bf16u*)p; p += 1536 * 1024;  // 3 x 512x512
  bf16u* WoT  = (bf16u*)p; p += 512 * 1024;
  bf16u* W1T  = (bf16u*)p; p += 2 * MB1;
  bf16u* W2T  = (bf16u*)p; p += 2 * MB1;
  bf16u* fcT  = (bf16u*)p; p += 512 * 1024;   // ~64 MB total
  bf16u* qb = qkvb;
  bf16u* kb = qkvb + MD;
  bf16u* vb = qkvb + 2 * MD;
  bf16u* pacc = hidb;

  cond_embed_kernel<<<dim3(NCOND, BATCH), 256, 0, stream>>>(
      conds, cW1, cb1, cW2, cb2, nullc, pos, x, xb);
  tok_embed_kernel<<<dim3(S_TOK, BATCH), 256, 0, stream>>>(toks, emb, pos, x, xb);

  dim3 gQKV(MROWS / 128, 1536 / 128);      // (32,12)
  dim3 gFF1(MROWS / 128, DINNER / 128);    // (32,16)
  dim3 gN512(MROWS / 64, DMODEL / 128);    // (64,4)

  for (int l = 0; l < NLAYER; l++) {
    wt_kernel<<<768, 256, 0, stream>>>(Wq, Wk, Wv, Wo, fW1, fW2,
        WqkvT, WqkvT + 262144, WqkvT + 524288, WoT, W1T, W2T, l);

    // fused QKV
    mgemm<4><<<gQKV, 256, 0, stream>>>(xb, WqkvT,
        bq + l * DMODEL, bk + l * DMODEL, bv + l * DMODEL, nullptr,
        nullptr, qkvb, MROWS, 1536, DMODEL, 4, nullptr, nullptr, nullptr);

    e_conv_kernel<<<(SEQ * DHEAD) / 1024, 256, 0, stream>>>(
        E + (size_t)l * SEQ * DHEAD, ebf);
    attn_part<<<2048, 256, 0, stream>>>(qb, kb, vb, ebf, toks, pacc, pstat);
    attn_combine<<<512, 256, 0, stream>>>(pacc, pstat, qb);

    // t1 = attn @ Wo + bo + x
    mgemm<2><<<gN512, 256, 0, stream>>>(qb, WoT,
        bo + l * DMODEL, nullptr, nullptr, x,
        t1, nullptr, MROWS, DMODEL, DMODEL, 1, nullptr, nullptr, nullptr);
    ln_kernel<<<MROWS, 256, 0, stream>>>(t1, ln1g + l * DMODEL, ln1b + l * DMODEL,
        out1, xb);

    // hid = relu(out1 @ W1 + b1) + chord
    mgemm<4><<<gFF1, 256, 0, stream>>>(xb, W1T,
        fb1 + l * DINNER, nullptr, nullptr, nullptr,
        nullptr, hidb, MROWS, DINNER, DMODEL, 2, ttc, ttcW, ttcb);
    // t1 = hid @ W2 + b2 + out1
    mgemm<2><<<gN512, 256, 0, stream>>>(hidb, W2T,
        fb2 + l * DMODEL, nullptr, nullptr, out1,
        t1, nullptr, MROWS, DMODEL, DINNER, 1, nullptr, nullptr, nullptr);
    ln_kernel<<<MROWS, 256, 0, stream>>>(t1, ln2g + l * DMODEL, ln2b + l * DMODEL,
        x, xb);
  }

  // logits = x @ fc_W + fc_b (fp32 out)
  wt_kernel<<<64, 256, 0, stream>>>(fcW, fcW, fcW, fcW, fcW, fcW,
      fcT, fcT, fcT, fcT, fcT, fcT, 0);
  mgemm<2><<<gN512, 256, 0, stream>>>(xb, fcT,
      fcb, nullptr, nullptr, nullptr,
      (float*)d_out, nullptr, MROWS, VOCAB, DMODEL, 3, nullptr, nullptr, nullptr);
}

// Round 7
// 1601.999 us; speedup vs baseline: 11.8281x; 1.1464x over previous
//
#include <hip/hip_runtime.h>
#include <hip/hip_bf16.h>
#include <math.h>

// ---- problem constants ----
#define BATCH  2
#define S_TOK  2046
#define NCOND  2
#define SEQ    2048
#define DMODEL 512
#define DINNER 2048
#define NHEAD  8
#define DHEAD  64
#define NLAYER 6
#define VOCAB  512
#define MROWS  (BATCH*SEQ)   // 4096 rows

typedef unsigned short bf16u;
typedef __attribute__((ext_vector_type(8))) short s8frag;   // 8 bf16 (4 VGPRs)
typedef __attribute__((ext_vector_type(4))) float f4frag;   // 4 fp32 acc

__device__ __forceinline__ float b2f(bf16u u) {
  union { unsigned int i; float f; } v; v.i = ((unsigned int)u) << 16; return v.f;
}
__device__ __forceinline__ bf16u f2b(float f) {
  union { float f; unsigned int i; } v; v.f = f;
  unsigned int x = v.i;
  return (bf16u)((x + 0x7fffu + ((x >> 16) & 1u)) >> 16);
}
__device__ __forceinline__ unsigned int pack2(float a, float b) {
  return (unsigned int)f2b(a) | ((unsigned int)f2b(b) << 16);
}

// ---------------------------------------------------------------------------
// All-layer weight transpose + bf16: dst[N][K] = src[K][N]. One launch.
// blocks: 6 layers x 768 (q64|k64|v64|o64|W1 256|W2 256) + 64 (fc) = 4672.
// ---------------------------------------------------------------------------
__global__ __launch_bounds__(256) void wt_all_kernel(
    const float* __restrict__ Wq, const float* __restrict__ Wk,
    const float* __restrict__ Wv, const float* __restrict__ Wo,
    const float* __restrict__ W1, const float* __restrict__ W2,
    const float* __restrict__ fcW,
    bf16u* __restrict__ qkvT, bf16u* __restrict__ oT,
    bf16u* __restrict__ w1T, bf16u* __restrict__ w2T, bf16u* __restrict__ fcT)
{
  int bid = blockIdx.x;
  const float* src; bf16u* dst; int N, K, kt, nt;
  if (bid < 6 * 768) {
    int L = bid / 768, t = bid - L * 768;
    if (t < 256) {
      int mat = t >> 6, tt = t & 63;
      const float* s4[4] = {Wq, Wk, Wv, Wo};
      src = s4[mat] + (size_t)L * DMODEL * DMODEL;
      dst = (mat < 3) ? (qkvT + (size_t)L * 786432 + (size_t)mat * 262144)
                      : (oT + (size_t)L * 262144);
      K = DMODEL; N = DMODEL; kt = tt >> 3; nt = tt & 7;
    } else if (t < 512) {
      int tt = t - 256;
      src = W1 + (size_t)L * DMODEL * DINNER; dst = w1T + (size_t)L * 1048576;
      K = DMODEL; N = DINNER; kt = tt >> 5; nt = tt & 31;
    } else {
      int tt = t - 512;
      src = W2 + (size_t)L * DINNER * DMODEL; dst = w2T + (size_t)L * 1048576;
      K = DINNER; N = DMODEL; kt = tt >> 3; nt = tt & 7;
    }
  } else {
    int tt = bid - 6 * 768;
    src = fcW; dst = fcT;
    K = DMODEL; N = VOCAB; kt = tt >> 3; nt = tt & 7;
  }
  __shared__ bf16u Ls[64][66];
  int tid = threadIdx.x;
  int c = tid & 63, r4 = tid >> 6;
#pragma unroll
  for (int i = 0; i < 16; i++) {
    int r = i * 4 + r4;
    Ls[r][c] = f2b(src[(size_t)(kt * 64 + r) * N + nt * 64 + c]);
  }
  __syncthreads();
#pragma unroll
  for (int i = 0; i < 16; i++) {
    int rr = i * 4 + r4;
    dst[(size_t)(nt * 64 + rr) * K + kt * 64 + c] = Ls[c][rr];
  }
}

// ---------------------------------------------------------------------------
// V transpose (bf16): vb[(b,i)][h*64+d] -> vbt[(b*8+h)*64+d][i]. 512 blocks.
// ---------------------------------------------------------------------------
__global__ __launch_bounds__(256) void vt_kernel(
    const bf16u* __restrict__ vb, bf16u* __restrict__ vbt)
{
  int bid = blockIdx.x;
  int b = bid >> 8, t = bid & 255;
  int it = t >> 3, h = t & 7;
  __shared__ bf16u Ls[64][66];
  int tid = threadIdx.x;
  int c = tid & 63, r4 = tid >> 6;
#pragma unroll
  for (int i = 0; i < 16; i++) {
    int r = i * 4 + r4;
    Ls[r][c] = vb[(size_t)(b * SEQ + it * 64 + r) * DMODEL + h * DHEAD + c];
  }
  __syncthreads();
#pragma unroll
  for (int i = 0; i < 16; i++) {
    int rr = i * 4 + r4;
    vbt[(size_t)((b * 8 + h) * DHEAD + rr) * SEQ + it * 64 + c] = Ls[c][rr];
  }
}

// ---------------------------------------------------------------------------
// MFMA GEMM, RB m-tiles/wave (4 -> 128x128, 2 -> 64x128).
// modes: 0 +bias->bf16 ; 1 +bias+Rb(bf16)->bf16 ; 2 relu(+bias)+chord->bf16 ;
//        3 +bias->fp32 ; 4 fused-QKV routing -> bf16 (3 slices)
// ---------------------------------------------------------------------------
template <int RB>
__global__ __launch_bounds__(256) void mgemm(
    const bf16u* __restrict__ A, const bf16u* __restrict__ Wt,
    const float* __restrict__ b0, const float* __restrict__ b1,
    const float* __restrict__ b2, const bf16u* __restrict__ Rb,
    float* __restrict__ Cf, bf16u* __restrict__ Cb,
    int M, int N, int K, int mode,
    const float* __restrict__ ttc, const float* __restrict__ ttcW,
    const float* __restrict__ ttcb)
{
  __shared__ bf16u Ab[RB * 32][40];
  __shared__ bf16u Bb[128][40];
  const int tid = threadIdx.x;
  const int lane = tid & 63, wave = tid >> 6;
  const int quad = lane >> 4, l16 = lane & 15;
  const int wm = wave >> 1, wn = wave & 1;
  const int row0 = blockIdx.x * (RB * 32), col0 = blockIdx.y * 128;

  f4frag acc[RB][4];
#pragma unroll
  for (int i = 0; i < RB; i++)
#pragma unroll
    for (int j = 0; j < 4; j++) acc[i][j] = (f4frag){0.f, 0.f, 0.f, 0.f};

  for (int k0 = 0; k0 < K; k0 += 32) {
    if (k0) __syncthreads();
#pragma unroll
    for (int i = 0; i < RB / 2; i++) {
      int c = tid + i * 256;
      int r = c >> 2, koff = (c & 3) * 8;
      *(uint4*)&Ab[r][koff] = *(const uint4*)&A[(size_t)(row0 + r) * K + k0 + koff];
    }
#pragma unroll
    for (int i = 0; i < 2; i++) {
      int c = tid + i * 256;
      int r = c >> 2, koff = (c & 3) * 8;
      *(uint4*)&Bb[r][koff] = *(const uint4*)&Wt[(size_t)(col0 + r) * K + k0 + koff];
    }
    __syncthreads();
    s8frag af[RB], bfr[4];
#pragma unroll
    for (int t = 0; t < RB; t++)
      af[t] = *(const s8frag*)&Ab[wm * (RB * 16) + t * 16 + l16][quad * 8];
#pragma unroll
    for (int t = 0; t < 4; t++)
      bfr[t] = *(const s8frag*)&Bb[wn * 64 + t * 16 + l16][quad * 8];
#pragma unroll
    for (int mt = 0; mt < RB; mt++)
#pragma unroll
      for (int nt = 0; nt < 4; nt++)
        acc[mt][nt] = __builtin_amdgcn_mfma_f32_16x16x32_bf16(
            af[mt], bfr[nt], acc[mt][nt], 0, 0, 0);
  }

#pragma unroll
  for (int mt = 0; mt < RB; mt++) {
#pragma unroll
    for (int r = 0; r < 4; r++) {
      int m = row0 + wm * (RB * 16) + mt * 16 + quad * 4 + r;
      float tval = 0.f;
      if (mode == 2) {
        int bb = m >> 11, s = m & (SEQ - 1);
        int sp = (s < NCOND) ? 0 : (s - NCOND);
        tval = 8.0f - ttc[bb * S_TOK + sp];
      }
#pragma unroll
      for (int nt = 0; nt < 4; nt++) {
        int n = col0 + wn * 64 + nt * 16 + l16;
        if (mode == 4) {
          int sel = n >> 9, nn = n & 511;
          float bv = (sel == 0) ? b0[nn] : ((sel == 1) ? b1[nn] : b2[nn]);
          Cb[(size_t)sel * MROWS * DMODEL + (size_t)m * DMODEL + nn]
              = f2b(acc[mt][nt][r] + bv);
        } else {
          float v = acc[mt][nt][r] + b0[n];
          if (mode == 1)      v += b2f(Rb[(size_t)m * N + n]);
          else if (mode == 2) v = fmaxf(v, 0.f) + tval * ttcW[n] + ttcb[n];
          if (mode == 3) Cf[(size_t)m * N + n] = v;
          else           Cb[(size_t)m * N + n] = f2b(v);
        }
      }
    }
  }
}

// ---------------------------------------------------------------------------
// LayerNorm over D=512 (bf16 in -> bf16 out), one row per block.
// ---------------------------------------------------------------------------
__global__ __launch_bounds__(256) void ln_kernel(
    const bf16u* __restrict__ X, const float* __restrict__ g,
    const float* __restrict__ bta, bf16u* __restrict__ Y)
{
  int row = blockIdx.x, tid = threadIdx.x;
  unsigned int pr = *(const unsigned int*)&X[(size_t)row * DMODEL + 2 * tid];
  float x0 = b2f((bf16u)(pr & 0xffff)), x1 = b2f((bf16u)(pr >> 16));
  __shared__ float red[8];
  int wv = tid >> 6, ln = tid & 63;
  float s = x0 + x1;
  for (int off = 32; off; off >>= 1) s += __shfl_xor(s, off);
  if (ln == 0) red[wv] = s;
  __syncthreads();
  float mu = (red[0] + red[1] + red[2] + red[3]) * (1.0f / DMODEL);
  float d0 = x0 - mu, d1 = x1 - mu;
  float vs = d0 * d0 + d1 * d1;
  for (int off = 32; off; off >>= 1) vs += __shfl_xor(vs, off);
  if (ln == 0) red[4 + wv] = vs;
  __syncthreads();
  float var = (red[4] + red[5] + red[6] + red[7]) * (1.0f / DMODEL);
  float rstd = rsqrtf(var + 1e-6f);
  float y0 = d0 * rstd * g[2 * tid]     + bta[2 * tid];
  float y1 = d1 * rstd * g[2 * tid + 1] + bta[2 * tid + 1];
  *(unsigned int*)&Y[(size_t)row * DMODEL + 2 * tid] = pack2(y0, y1);
}

// ---------------------------------------------------------------------------
__global__ __launch_bounds__(256) void tok_embed_kernel(
    const int* __restrict__ toks, const float* __restrict__ emb,
    const float* __restrict__ pos, bf16u* __restrict__ xb)
{
  int sp = blockIdx.x, b = blockIdx.y;
  int s = sp + NCOND;
  int tok = toks[b * S_TOK + sp];
  const float* er = emb + (size_t)tok * DMODEL;
  const float* pr = pos + (size_t)s * DMODEL;
  size_t ro = ((size_t)b * SEQ + s) * DMODEL;
  int d = threadIdx.x * 2;
  float v0 = er[d]     * 22.62741699796952f + pr[d];
  float v1 = er[d + 1] * 22.62741699796952f + pr[d + 1];
  *(unsigned int*)&xb[ro + d] = pack2(v0, v1);
}

// ---------------------------------------------------------------------------
__global__ __launch_bounds__(256) void cond_embed_kernel(
    const float* __restrict__ conds, const float* __restrict__ W1,
    const float* __restrict__ b1, const float* __restrict__ W2w,
    const float* __restrict__ b2, const float* __restrict__ nullc,
    const float* __restrict__ pos, bf16u* __restrict__ xb)
{
  int ci = blockIdx.x, b = blockIdx.y, tid = threadIdx.x;
  float c = conds[b * NCOND + ci];
  bool cn = isnan(c);
  float cm = cn ? 0.f : c;
  __shared__ float h1[DMODEL / 2];
  h1[tid] = fmaxf(cm * W1[ci * (DMODEL/2) + tid] + b1[ci * (DMODEL/2) + tid], 0.f);
  __syncthreads();
  for (int d = tid; d < DMODEL; d += 256) {
    float acc = b2[ci * DMODEL + d];
    for (int i = 0; i < DMODEL / 2; i++)
      acc = fmaf(h1[i], W2w[((size_t)ci * (DMODEL/2) + i) * DMODEL + d], acc);
    float ce = cn ? nullc[ci * DMODEL + d] : acc;
    xb[((size_t)b * SEQ + ci) * DMODEL + d] = f2b(ce + pos[(size_t)ci * DMODEL + d]);
  }
}

// ---------------------------------------------------------------------------
// E (fp32, all 6 layers) -> bf16.
// ---------------------------------------------------------------------------
__global__ __launch_bounds__(256) void e_conv_kernel(
    const float* __restrict__ E, bf16u* __restrict__ Eb)
{
  int i = (blockIdx.x * 256 + threadIdx.x) * 4;
  float4 v = *(const float4*)&E[i];
  ushort4 o;
  o.x = f2b(v.x); o.y = f2b(v.y); o.z = f2b(v.z); o.w = f2b(v.w);
  *(ushort4*)&Eb[i] = o;
}

// ---------------------------------------------------------------------------
// Split-K MFMA flash attention v3. Block = (b,h, q-tile it, chunk c<=8 steps).
// QE gathered from MFMA C-frags via shuffle (no LDS round-trip); per-wave
// 80-col QE window (5 frags); rolling 128-row E ring (phys = m & 127);
// V pre-transposed in global (vbt).
// ---------------------------------------------------------------------------
__global__ __launch_bounds__(256) void attn_part(
    const bf16u* __restrict__ Q, const bf16u* __restrict__ K,
    const bf16u* __restrict__ Vt_g, const bf16u* __restrict__ Eb16,
    const int* __restrict__ toks, bf16u* __restrict__ pacc,
    float* __restrict__ pstat)
{
  const int bid = blockIdx.x;
  const int g  = bid >> 7;          // (b,h)
  const int it = (bid >> 2) & 31;   // q-tile
  const int c  = bid & 3;           // key chunk
  if (8 * c > it) return;
  const int b = g >> 3, h = g & 7;
  const int i0 = it * 64;

  __shared__ bf16u Kb[64][72];
  __shared__ bf16u Vt[64][72];
  __shared__ bf16u Ebs[128][72];
  __shared__ bf16u Ps[64][72];
  __shared__ float padv[64];

  const int tid  = threadIdx.x;
  const int lane = tid & 63;
  const int wave = tid >> 6;
  const int quad = lane >> 4;
  const int l16  = lane & 15;

  const bf16u* qr = Q + ((size_t)(b * SEQ + i0 + wave * 16 + l16)) * DMODEL + h * DHEAD;
  s8frag q0 = *(const s8frag*)&qr[quad * 8];
  s8frag q1 = *(const s8frag*)&qr[32 + quad * 8];

  float m_run[4], l_run[4];
  f4frag acc[4];
#pragma unroll
  for (int r = 0; r < 4; r++) { m_run[r] = -1e30f; l_run[r] = 0.f; }
#pragma unroll
  for (int dt = 0; dt < 4; dt++) acc[dt] = (f4frag){0.f, 0.f, 0.f, 0.f};

  const int js0 = 8 * c;
  const int jsE = min(8 * c + 8, it + 1);
  const size_t vtbase = (size_t)(g * DHEAD) * SEQ;

  for (int js = js0; js < jsE; js++) {
    const int j0 = js * 64;
    const int m0 = 1984 - i0 + j0;   // E row of band col 0
    __syncthreads();

    // K tile (2 x uint4 / thread)
#pragma unroll
    for (int e = 0; e < 2; e++) {
      int cc = e * 256 + tid;
      int jr = cc >> 3, doff = (cc & 7) * 8;
      *(uint4*)&Kb[jr][doff] =
          *(const uint4*)&K[((size_t)(b * SEQ + j0 + jr)) * DMODEL + h * DHEAD + doff];
    }
    // V^T tile from pre-transposed global (2 x uint4 / thread)
#pragma unroll
    for (int e = 0; e < 2; e++) {
      int cc = e * 256 + tid;
      int dr = cc >> 3, joff = (cc & 7) * 8;
      *(uint4*)&Vt[dr][joff] =
          *(const uint4*)&Vt_g[vtbase + (size_t)dr * SEQ + j0 + joff];
    }
    // E ring: first step fill 128 rows, then 64 new rows
    if (js == js0) {
#pragma unroll
      for (int e = 0; e < 4; e++) {
        int cc = e * 256 + tid;
        int er = cc >> 3, doff = (cc & 7) * 8;
        int m = m0 + er; int row = m > SEQ - 1 ? SEQ - 1 : m;
        *(uint4*)&Ebs[m & 127][doff] = *(const uint4*)&Eb16[(size_t)row * DHEAD + doff];
      }
    } else {
#pragma unroll
      for (int e = 0; e < 2; e++) {
        int cc = e * 256 + tid;
        int er = 64 + (cc >> 3), doff = (cc & 7) * 8;
        int m = m0 + er; int row = m > SEQ - 1 ? SEQ - 1 : m;
        *(uint4*)&Ebs[m & 127][doff] = *(const uint4*)&Eb16[(size_t)row * DHEAD + doff];
      }
    }
    if (tid < 64) {
      int j = j0 + tid;
      bool pad = (j >= NCOND) && (toks[b * S_TOK + j - NCOND] == 0);
      padv[tid] = pad ? -1e30f : 0.f;
    }
    __syncthreads();

    // QK^T
    f4frag sc[4];
#pragma unroll
    for (int nt = 0; nt < 4; nt++) {
      s8frag k0 = *(const s8frag*)&Kb[nt * 16 + l16][quad * 8];
      s8frag k1 = *(const s8frag*)&Kb[nt * 16 + l16][32 + quad * 8];
      f4frag cc = (f4frag){0.f, 0.f, 0.f, 0.f};
      cc = __builtin_amdgcn_mfma_f32_16x16x32_bf16(q0, k0, cc, 0, 0, 0);
      cc = __builtin_amdgcn_mfma_f32_16x16x32_bf16(q1, k1, cc, 0, 0, 0);
      sc[nt] = cc;
    }

    // QE: 5 frags covering band cols [(3-wave)*16, (8-wave)*16)
    f4frag qef[5];
#pragma unroll
    for (int f = 0; f < 5; f++) {
      int ct = f + 3 - wave;
      int m = m0 + ct * 16 + l16;
      const bf16u* erow = &Ebs[m & 127][0];
      s8frag e0 = *(const s8frag*)&erow[quad * 8];
      s8frag e1 = *(const s8frag*)&erow[32 + quad * 8];
      f4frag cc = (f4frag){0.f, 0.f, 0.f, 0.f};
      cc = __builtin_amdgcn_mfma_f32_16x16x32_bf16(q0, e0, cc, 0, 0, 0);
      cc = __builtin_amdgcn_mfma_f32_16x16x32_bf16(q1, e1, cc, 0, 0, 0);
      qef[f] = cc;
    }

    // scores + online softmax; QE gathered by shuffle.
    float s[4][4], mx[4];
#pragma unroll
    for (int r = 0; r < 4; r++) {
      int rloc = wave * 16 + quad * 4 + r;
      int ig = i0 + rloc;
      int v = 63 - 16 * wave + l16 - quad * 4 - r;
      int srcl = (lane & 48) | (v & 15);
      bool hi = (l16 > quad * 4 + r);
#pragma unroll
      for (int nt = 0; nt < 4; nt++) {
        float qeLo = __shfl(qef[nt][r], srcl);
        float qeHi = __shfl(qef[nt + 1][r], srcl);
        float qe = hi ? qeHi : qeLo;
        int jl = nt * 16 + l16;
        float sv = (sc[nt][r] + qe) * 0.125f + padv[jl];
        if (j0 + jl > ig) sv = -1e30f;
        s[nt][r] = sv;
      }
      float m = fmaxf(fmaxf(s[0][r], s[1][r]), fmaxf(s[2][r], s[3][r]));
      m = fmaxf(m, __shfl_xor(m, 1));
      m = fmaxf(m, __shfl_xor(m, 2));
      m = fmaxf(m, __shfl_xor(m, 4));
      m = fmaxf(m, __shfl_xor(m, 8));
      mx[r] = m;
    }
    float alpha[4];
#pragma unroll
    for (int r = 0; r < 4; r++) {
      float m_new = fmaxf(m_run[r], mx[r]);
      alpha[r] = __expf(m_run[r] - m_new);
      float psum = 0.f;
      int rloc = wave * 16 + quad * 4 + r;
#pragma unroll
      for (int nt = 0; nt < 4; nt++) {
        float p = __expf(s[nt][r] - m_new);
        Ps[rloc][nt * 16 + l16] = f2b(p);
        psum += p;
      }
      psum += __shfl_xor(psum, 1);
      psum += __shfl_xor(psum, 2);
      psum += __shfl_xor(psum, 4);
      psum += __shfl_xor(psum, 8);
      l_run[r] = l_run[r] * alpha[r] + psum;
      m_run[r] = m_new;
    }
#pragma unroll
    for (int dt = 0; dt < 4; dt++)
#pragma unroll
      for (int r = 0; r < 4; r++) acc[dt][r] *= alpha[r];

    // P @ V
    s8frag p0 = *(const s8frag*)&Ps[wave * 16 + l16][quad * 8];
    s8frag p1 = *(const s8frag*)&Ps[wave * 16 + l16][32 + quad * 8];
#pragma unroll
    for (int dt = 0; dt < 4; dt++) {
      s8frag v0 = *(const s8frag*)&Vt[dt * 16 + l16][quad * 8];
      s8frag v1 = *(const s8frag*)&Vt[dt * 16 + l16][32 + quad * 8];
      acc[dt] = __builtin_amdgcn_mfma_f32_16x16x32_bf16(p0, v0, acc[dt], 0, 0, 0);
      acc[dt] = __builtin_amdgcn_mfma_f32_16x16x32_bf16(p1, v1, acc[dt], 0, 0, 0);
    }
  }

  // write partials
#pragma unroll
  for (int r = 0; r < 4; r++) {
    int rloc = wave * 16 + quad * 4 + r;
    if (l16 == 0) {
      pstat[(size_t)bid * 128 + rloc]      = m_run[r];
      pstat[(size_t)bid * 128 + 64 + rloc] = l_run[r];
    }
#pragma unroll
    for (int dt = 0; dt < 4; dt++)
      pacc[(size_t)bid * 4096 + rloc * 64 + dt * 16 + l16] = f2b(acc[dt][r]);
  }
}

// ---------------------------------------------------------------------------
// Merge <=4 chunk partials per (b,h,q-tile); write O (bf16) into qb.
// ---------------------------------------------------------------------------
__global__ __launch_bounds__(256) void attn_combine(
    const bf16u* __restrict__ pacc, const float* __restrict__ pstat,
    bf16u* __restrict__ O)
{
  int bid = blockIdx.x;             // g*32 + it
  int g = bid >> 5, it = bid & 31;
  int b = g >> 3, h = g & 7;
  int i0 = it * 64;
  int nc = (it >> 3) + 1;
  int tid = threadIdx.x;
  int row = tid >> 2, ql = tid & 3;

  float m_tot = -1e30f;
  float mc[4], lc[4];
#pragma unroll
  for (int c = 0; c < 4; c++) {
    if (c < nc) {
      size_t pb = (size_t)(bid * 4 + c) * 128;
      mc[c] = pstat[pb + row];
      lc[c] = pstat[pb + 64 + row];
      m_tot = fmaxf(m_tot, mc[c]);
    }
  }
  float l_tot = 0.f, w[4];
#pragma unroll
  for (int c = 0; c < 4; c++) {
    if (c < nc) { w[c] = __expf(mc[c] - m_tot); l_tot += w[c] * lc[c]; }
    else w[c] = 0.f;
  }
  float inv = 1.0f / l_tot;

  float out[16];
#pragma unroll
  for (int k = 0; k < 16; k++) out[k] = 0.f;
#pragma unroll
  for (int c = 0; c < 4; c++) {
    if (c >= nc) break;
    const bf16u* pa = pacc + (size_t)(bid * 4 + c) * 4096 + row * 64 + ql * 16;
#pragma unroll
    for (int k = 0; k < 16; k++) out[k] += w[c] * b2f(pa[k]);
  }
  bf16u* ob = O + ((size_t)(b * SEQ + i0 + row)) * DMODEL + h * DHEAD + ql * 16;
#pragma unroll
  for (int k = 0; k < 16; k++) ob[k] = f2b(out[k] * inv);
}

// ---------------------------------------------------------------------------
extern "C" void kernel_launch(void* const* d_in, const int* in_sizes, int n_in,
                              void* d_out, int out_size, void* d_ws, size_t ws_size,
                              hipStream_t stream) {
  const int*   toks  = (const int*)  d_in[0];
  const float* conds = (const float*)d_in[1];
  const float* ttc   = (const float*)d_in[2];
  const float* emb   = (const float*)d_in[3];
  const float* pos   = (const float*)d_in[4];
  const float* cW1   = (const float*)d_in[5];
  const float* cb1   = (const float*)d_in[6];
  const float* cW2   = (const float*)d_in[7];
  const float* cb2   = (const float*)d_in[8];
  const float* nullc = (const float*)d_in[9];
  const float* ttcW  = (const float*)d_in[10];
  const float* ttcb  = (const float*)d_in[11];
  const float* Wq    = (const float*)d_in[12];
  const float* Wk    = (const float*)d_in[13];
  const float* Wv    = (const float*)d_in[14];
  const float* Wo    = (const float*)d_in[15];
  const float* bq    = (const float*)d_in[16];
  const float* bk    = (const float*)d_in[17];
  const float* bv    = (const float*)d_in[18];
  const float* bo    = (const float*)d_in[19];
  const float* E     = (const float*)d_in[20];
  const float* fW1   = (const float*)d_in[21];
  const float* fb1   = (const float*)d_in[22];
  const float* fW2   = (const float*)d_in[23];
  const float* fb2   = (const float*)d_in[24];
  const float* ln1g  = (const float*)d_in[25];
  const float* ln1b  = (const float*)d_in[26];
  const float* ln2g  = (const float*)d_in[27];
  const float* ln2b  = (const float*)d_in[28];
  const float* fcW   = (const float*)d_in[29];
  const float* fcb   = (const float*)d_in[30];

  const size_t MB1 = 1024 * 1024;
  const size_t MD = (size_t)MROWS * DMODEL;
  char* p = (char*)d_ws;
  bf16u* xb    = (bf16u*)p; p += 4 * MB1;
  bf16u* qkvb  = (bf16u*)p; p += 12 * MB1;   // qb | kb | vb
  bf16u* hidb  = (bf16u*)p; p += 16 * MB1;   // FFN hidden / pacc alias
  float* pstat = (float*)p; p += 1 * MB1;
  bf16u* vbt   = (bf16u*)p; p += 4 * MB1;    // V transposed
  bf16u* ebf   = (bf16u*)p; p += 1536 * 1024;   // E bf16, 6 layers
  bf16u* WqkvT = (bf16u*)p; p += 9 * MB1;
  bf16u* WoT   = (bf16u*)p; p += 3 * MB1;
  bf16u* W1T   = (bf16u*)p; p += 12 * MB1;
  bf16u* W2T   = (bf16u*)p; p += 12 * MB1;
  bf16u* fcT   = (bf16u*)p; p += 512 * 1024;    // total 75 MB
  bf16u* qb = qkvb;
  bf16u* kb = qkvb + MD;        // out1b aliases kb (disjoint lifetimes)
  bf16u* vb = qkvb + 2 * MD;    // t1b aliases vb (disjoint lifetimes)
  bf16u* out1b = kb;
  bf16u* t1b   = vb;
  bf16u* pacc  = hidb;

  // ---- setup: embeds + all-layer weight transposes + E conversion ----
  cond_embed_kernel<<<dim3(NCOND, BATCH), 256, 0, stream>>>(
      conds, cW1, cb1, cW2, cb2, nullc, pos, xb);
  tok_embed_kernel<<<dim3(S_TOK, BATCH), 256, 0, stream>>>(toks, emb, pos, xb);
  wt_all_kernel<<<6 * 768 + 64, 256, 0, stream>>>(Wq, Wk, Wv, Wo, fW1, fW2, fcW,
      WqkvT, WoT, W1T, W2T, fcT);
  e_conv_kernel<<<(NLAYER * SEQ * DHEAD) / 1024, 256, 0, stream>>>(E, ebf);

  dim3 gQKV(MROWS / 128, 1536 / 128);      // (32,12)
  dim3 gFF1(MROWS / 128, DINNER / 128);    // (32,16)
  dim3 gN512(MROWS / 64, DMODEL / 128);    // (64,4)

  for (int l = 0; l < NLAYER; l++) {
    // fused QKV
    mgemm<4><<<gQKV, 256, 0, stream>>>(xb, WqkvT + (size_t)l * 786432,
        bq + l * DMODEL, bk + l * DMODEL, bv + l * DMODEL, nullptr,
        nullptr, qkvb, MROWS, 1536, DMODEL, 4, nullptr, nullptr, nullptr);

    vt_kernel<<<512, 256, 0, stream>>>(vb, vbt);
    attn_part<<<2048, 256, 0, stream>>>(qb, kb, vbt,
        ebf + (size_t)l * SEQ * DHEAD, toks, pacc, pstat);
    attn_combine<<<512, 256, 0, stream>>>(pacc, pstat, qb);

    // t1 = attn @ Wo + bo + x
    mgemm<2><<<gN512, 256, 0, stream>>>(qb, WoT + (size_t)l * 262144,
        bo + l * DMODEL, nullptr, nullptr, xb,
        nullptr, t1b, MROWS, DMODEL, DMODEL, 1, nullptr, nullptr, nullptr);
    ln_kernel<<<MROWS, 256, 0, stream>>>(t1b, ln1g + l * DMODEL, ln1b + l * DMODEL,
        out1b);

    // hid = relu(out1 @ W1 + b1) + chord
    mgemm<4><<<gFF1, 256, 0, stream>>>(out1b, W1T + (size_t)l * 1048576,
        fb1 + l * DINNER, nullptr, nullptr, nullptr,
        nullptr, hidb, MROWS, DINNER, DMODEL, 2, ttc, ttcW, ttcb);
    // t1 = hid @ W2 + b2 + out1
    mgemm<2><<<gN512, 256, 0, stream>>>(hidb, W2T + (size_t)l * 1048576,
        fb2 + l * DMODEL, nullptr, nullptr, out1b,
        nullptr, t1b, MROWS, DMODEL, DINNER, 1, nullptr, nullptr, nullptr);
    ln_kernel<<<MROWS, 256, 0, stream>>>(t1b, ln2g + l * DMODEL, ln2b + l * DMODEL,
        xb);
  }

  // logits = x @ fc_W + fc_b (fp32 out)
  mgemm<2><<<gN512, 256, 0, stream>>>(xb, fcT,
      fcb, nullptr, nullptr, nullptr,
      (float*)d_out, nullptr, MROWS, VOCAB, DMODEL, 3, nullptr, nullptr, nullptr);
}